// Round 5
// baseline (791.136 us; speedup 1.0000x reference)
//
#include <hip/hip_runtime.h>
#include <math.h>

#define NNODES 50000
#define NEDGES 800000
#define NGRAPH 512
#define FIN    256
#define H1     256
#define H2     256
#define H3     512
#define FPOUT  2048

typedef __attribute__((ext_vector_type(8))) short short8;
typedef __attribute__((ext_vector_type(8))) _Float16 half8;
typedef __attribute__((ext_vector_type(4))) float floatx4;
typedef __attribute__((ext_vector_type(4))) unsigned short ushx4;

// fp16 helpers: v_cvt_f16_f32 is RNE on gfx950
__device__ inline float h2f(ushort u) { return (float)__builtin_bit_cast(_Float16, u); }
__device__ inline ushort f2h(float x) { return __builtin_bit_cast(ushort, (_Float16)x); }
// Dekker split: a = hi + lo with hi = RNE-fp16(a); lo carries ~11 more mantissa bits.
__device__ inline void split2h(float a, ushort& h, ushort& l) {
    _Float16 hh = (_Float16)a;
    h = __builtin_bit_cast(ushort, hh);
    l = f2h(a - (float)hh);
}

// ---------------- utility kernels ----------------

__global__ __launch_bounds__(256) void zero_i32(int* p, int n) {
    int i = blockIdx.x * 256 + threadIdx.x;
    if (i < n) p[i] = 0;
}

// count degrees AND record each edge's rank within its destination (atomic returns old)
__global__ __launch_bounds__(256) void count_deg(const int* __restrict__ ei, int* __restrict__ degi,
                                                 int* __restrict__ rank, int e_total) {
    int e = blockIdx.x * 256 + threadIdx.x;
    if (e >= e_total) return;
    int d = ei[e_total + e];
    rank[e] = atomicAdd(&degi[d], 1);
}

__global__ __launch_bounds__(256) void calc_dis(const int* __restrict__ degi, float* __restrict__ dis, int n) {
    int i = blockIdx.x * 256 + threadIdx.x;
    if (i < n) dis[i] = rsqrtf((float)(degi[i] + 1));   // +1 self loop
}

__global__ __launch_bounds__(256) void scanA(const int* __restrict__ degi, int* __restrict__ offs,
                                             int* __restrict__ partials, int n) {
    __shared__ int sm[256];
    int t = threadIdx.x, idx = blockIdx.x * 256 + t;
    int v = (idx < n) ? degi[idx] : 0;
    sm[t] = v; __syncthreads();
    for (int d = 1; d < 256; d <<= 1) {
        int add = (t >= d) ? sm[t - d] : 0;
        __syncthreads();
        sm[t] += add;
        __syncthreads();
    }
    if (idx < n) offs[idx + 1] = sm[t];
    if (t == 255) partials[blockIdx.x] = sm[255];
}

__global__ __launch_bounds__(256) void scanB(int* __restrict__ partials, int nb) {
    __shared__ int sm[256];
    int t = threadIdx.x;
    int v = (t < nb) ? partials[t] : 0;
    sm[t] = v; __syncthreads();
    for (int d = 1; d < 256; d <<= 1) {
        int add = (t >= d) ? sm[t - d] : 0;
        __syncthreads();
        sm[t] += add;
        __syncthreads();
    }
    if (t < nb) partials[t] = sm[t] - v;   // exclusive
}

__global__ __launch_bounds__(256) void scanC(int* __restrict__ offs, const int* __restrict__ partials, int n) {
    int idx = blockIdx.x * 256 + threadIdx.x;
    if (idx < n) offs[idx + 1] += partials[blockIdx.x];
    if (idx == 0) offs[0] = 0;
}

// atomic-free scatter: pos = offs[d] + rank[e]; one packed 8B store per edge
__global__ __launch_bounds__(256) void fill_csr(const int* __restrict__ ei, const float* __restrict__ dis,
                                                const int* __restrict__ offs, const int* __restrict__ rank,
                                                int2* __restrict__ csr_pair, int e_total) {
    int e = blockIdx.x * 256 + threadIdx.x;
    if (e >= e_total) return;
    int s = ei[e];
    int d = ei[e_total + e];
    int pos = offs[d] + rank[e];
    int2 pr;
    pr.x = s;
    pr.y = __float_as_int(dis[s] * dis[d]);
    csr_pair[pos] = pr;
}

// W[K][N] fp32 -> Wt_hi[N][K], Wt_lo[N][K] (fp16 Dekker pair): LDS-tiled transpose
__global__ __launch_bounds__(256) void wsplit_t(const float* __restrict__ W, ushort* __restrict__ hi,
                                                ushort* __restrict__ lo, int K, int N) {
    __shared__ float sm[32][33];
    int tx = threadIdx.x & 31, ty = threadIdx.x >> 5;   // 32 x 8
    int n0 = blockIdx.x * 32, k0 = blockIdx.y * 32;
    #pragma unroll
    for (int j = 0; j < 32; j += 8)
        sm[ty + j][tx] = W[(size_t)(k0 + ty + j) * N + n0 + tx];
    __syncthreads();
    #pragma unroll
    for (int j = 0; j < 32; j += 8) {
        float a = sm[tx][ty + j];
        ushort h, l; split2h(a, h, l);
        size_t o = (size_t)(n0 + ty + j) * K + k0 + tx;
        hi[o] = h; lo[o] = l;
    }
}

// x fp32 -> fp16 table, CHUNK-MAJOR layout [8][NNODES][32]:
// element (node n, feat f) -> xh[((f>>5)*NNODES + n)*32 + (f&31)]
__global__ __launch_bounds__(256) void conv_f16(const float* __restrict__ x, ushort* __restrict__ xh, int total4) {
    int i = blockIdx.x * 256 + threadIdx.x;
    if (i >= total4) return;
    int n  = i >> 6;          // node
    int f4 = i & 63;          // float-quad within row (f = f4*4)
    float4 a = ((const float4*)x)[i];
    ushx4 h = {f2h(a.x), f2h(a.y), f2h(a.z), f2h(a.w)};
    size_t o4 = (((size_t)(f4 >> 3) * NNODES + n) * 32 + (f4 & 7) * 4) >> 2;  // ushx4 index
    ((ushx4*)xh)[o4] = h;
}

// ---------------- MFMA fp16 GEMM: BK=64, XOR-swizzled LDS, XCD-chunked blocks ----------------
// SPLIT=0: C = relu(A @ B^T + bias), single fp16 operands, 1 MFMA per frag pair.
// SPLIT=1: fp16 Dekker pairs, 3 MFMAs: Ah*Bh + Ah*Bl + Al*Bh (~fp32-accurate). Head GEMM.
// ACC=1: store raw acc to partial buffer C + z*M*N (split-K, finish kernel applies bias/relu).
// outmode 1: write fp16 activation table in CHUNK-MAJOR [N/32][M][32] layout.
// KSPAN: compile-time K-range per z-slice. K = runtime row stride.
template<int SPLIT, int ACC, int KSPAN>
__global__ __launch_bounds__(256) void gemm_f16(const ushort* __restrict__ Ahp, const ushort* __restrict__ Alp,
                                                const ushort* __restrict__ Bhp, const ushort* __restrict__ Blp,
                                                float* __restrict__ C, ushort* __restrict__ Ch,
                                                const float* __restrict__ bias,
                                                int M, int N, int K, int do_relu, int outmode) {
    __shared__ _Float16 lsA[128 * 64];
    __shared__ _Float16 lsB[128 * 64];
    __shared__ _Float16 lsAl[SPLIT ? 128 * 64 : 8];
    __shared__ _Float16 lsBl[SPLIT ? 128 * 64 : 8];
    const _Float16* Ah = (const _Float16*)Ahp;
    const _Float16* Al = (const _Float16*)Alp;
    const _Float16* Bh = (const _Float16*)Bhp;
    const _Float16* Bl = (const _Float16*)Blp;

    int tid = threadIdx.x;
    int w = tid >> 6, lane = tid & 63;
    int quad = lane >> 4, lr = lane & 15;
    int wm = w & 1, wn = w >> 1;

    // bijective XCD-chunked swizzle (m204): same row-panel's col-tiles land on one XCD
    int gx = gridDim.x;
    int orig = blockIdx.y * gx + blockIdx.x;
    int nwg = gx * gridDim.y;
    int xcd = orig & 7, slot = orig >> 3;
    int q = nwg >> 3, r = nwg & 7;
    int wid = (xcd < r ? xcd * (q + 1) : r * (q + 1) + (xcd - r) * q) + slot;
    int row0 = (wid / gx) * 128, col0 = (wid % gx) * 128;
    int kb = blockIdx.z * KSPAN;

    floatx4 acc[4][4];
    #pragma unroll
    for (int i = 0; i < 4; ++i)
        #pragma unroll
        for (int j = 0; j < 4; ++j)
            acc[i][j] = (floatx4){0.f, 0.f, 0.f, 0.f};

    const half8 zer = {};
    int srow = tid >> 3;                         // 0..31 (chunk adds +32)
    int sgran = tid & 7;                         // logical 16B granule within BK=64
    int skk = sgran * 8;                         // logical k offset (halves)
    int sgx = (sgran ^ (srow & 7)) * 8;          // swizzled LDS granule offset (halves)

    half8 pa[4], pb[4], pal[4], pbl[4];
    // prologue: load k-step 0
    #pragma unroll
    for (int c = 0; c < 4; ++c) {
        int row = c * 32 + srow;
        bool mok = (row0 + row) < M;
        size_t aoff = (size_t)(row0 + row) * K + kb + skk;
        pa[c] = mok ? *(const half8*)(Ah + aoff) : zer;
        if constexpr (SPLIT) pal[c] = mok ? *(const half8*)(Al + aoff) : zer;
        size_t boff = (size_t)(col0 + row) * K + kb + skk;
        pb[c] = *(const half8*)(Bh + boff);
        if constexpr (SPLIT) pbl[c] = *(const half8*)(Bl + boff);
    }

    for (int k0 = kb; k0 < kb + KSPAN; k0 += 64) {
        // commit prefetched step to LDS (swizzled granule)
        #pragma unroll
        for (int c = 0; c < 4; ++c) {
            int lo = (c * 32 + srow) * 64 + sgx;
            *(half8*)(lsA + lo) = pa[c];
            *(half8*)(lsB + lo) = pb[c];
            if constexpr (SPLIT) { *(half8*)(lsAl + lo) = pal[c]; *(half8*)(lsBl + lo) = pbl[c]; }
        }
        __syncthreads();
        // issue next step's global loads — overlap with the MFMA section below
        if (k0 + 64 < kb + KSPAN) {
            #pragma unroll
            for (int c = 0; c < 4; ++c) {
                int row = c * 32 + srow;
                bool mok = (row0 + row) < M;
                size_t aoff = (size_t)(row0 + row) * K + k0 + 64 + skk;
                pa[c] = mok ? *(const half8*)(Ah + aoff) : zer;
                if constexpr (SPLIT) pal[c] = mok ? *(const half8*)(Al + aoff) : zer;
                size_t boff = (size_t)(col0 + row) * K + k0 + 64 + skk;
                pb[c] = *(const half8*)(Bh + boff);
                if constexpr (SPLIT) pbl[c] = *(const half8*)(Bl + boff);
            }
        }
        #pragma unroll
        for (int kk = 0; kk < 2; ++kk) {
            half8 af[4], afl[4];
            #pragma unroll
            for (int mt = 0; mt < 4; ++mt) {
                int row = wm * 64 + mt * 16 + lr;
                int ao = row * 64 + (((kk * 4 + quad) ^ (row & 7)) << 3);
                af[mt] = *(const half8*)(lsA + ao);
                if constexpr (SPLIT) afl[mt] = *(const half8*)(lsAl + ao);
            }
            #pragma unroll
            for (int nt = 0; nt < 4; ++nt) {
                int row = wn * 64 + nt * 16 + lr;
                int bo = row * 64 + (((kk * 4 + quad) ^ (row & 7)) << 3);
                half8 bf = *(const half8*)(lsB + bo);
                half8 bfl;
                if constexpr (SPLIT) bfl = *(const half8*)(lsBl + bo);
                #pragma unroll
                for (int mt = 0; mt < 4; ++mt) {
                    acc[mt][nt] = __builtin_amdgcn_mfma_f32_16x16x32_f16(af[mt], bf, acc[mt][nt], 0, 0, 0);
                    if constexpr (SPLIT) {
                        acc[mt][nt] = __builtin_amdgcn_mfma_f32_16x16x32_f16(af[mt], bfl, acc[mt][nt], 0, 0, 0);
                        acc[mt][nt] = __builtin_amdgcn_mfma_f32_16x16x32_f16(afl[mt], bf, acc[mt][nt], 0, 0, 0);
                    }
                }
            }
        }
        __syncthreads();
    }

    size_t zoff = ACC ? (size_t)blockIdx.z * M * N : 0;
    #pragma unroll
    for (int mt = 0; mt < 4; ++mt) {
        #pragma unroll
        for (int rr = 0; rr < 4; ++rr) {
            int row = row0 + wm * 64 + mt * 16 + quad * 4 + rr;
            if (row >= M) continue;
            #pragma unroll
            for (int nt = 0; nt < 4; ++nt) {
                int col = col0 + wn * 64 + nt * 16 + lr;
                float v = acc[mt][nt][rr];
                if (!ACC) {
                    v += bias[col];
                    if (do_relu) v = v > 0.f ? v : 0.f;
                }
                if (outmode) Ch[((size_t)(col >> 5) * M + row) * 32 + (col & 31)] = f2h(v);
                else         C[zoff + (size_t)row * N + col] = v;
            }
        }
    }
}

// finish for split-K head: out = relu(sum_z partials + bias), vectorized float4
__global__ __launch_bounds__(256) void head_fin(const float* __restrict__ part, const float* __restrict__ bo,
                                                float* __restrict__ out) {
    int i4 = blockIdx.x * 256 + threadIdx.x;          // element-quad index
    const int TOT4 = NGRAPH * FPOUT / 4;
    if (i4 >= TOT4) return;
    int col4 = i4 & (FPOUT / 4 - 1);
    const size_t STRIDE4 = (size_t)NGRAPH * FPOUT / 4;
    const float4* p = (const float4*)part;
    float4 a = p[i4];
    float4 b = p[i4 + STRIDE4];
    float4 c = p[i4 + 2 * STRIDE4];
    float4 d = p[i4 + 3 * STRIDE4];
    float4 bb = ((const float4*)bo)[col4];
    float4 o;
    o.x = a.x + b.x + c.x + d.x + bb.x; o.x = o.x > 0.f ? o.x : 0.f;
    o.y = a.y + b.y + c.y + d.y + bb.y; o.y = o.y > 0.f ? o.y : 0.f;
    o.z = a.z + b.z + c.z + d.z + bb.z; o.z = o.z > 0.f ? o.z : 0.f;
    o.w = a.w + b.w + c.w + d.w + bb.w; o.w = o.w > 0.f ? o.w : 0.f;
    ((float4*)out)[i4] = o;
}

// ---------------- aggregation: feature-chunked, XCD-affine ----------------
// xh is chunk-major [8][NNODES][32]. chunk = blockIdx.x & 7 -> (round-robin dispatch)
// each XCD's blocks gather only their 3.2 MB slice -> L2-resident.
// One wave per node: 16 edges x 4 lanes x 16B per trip; logical edge 0 = self-loop.
// Cross-lane sum over the 16 edge-groups via shfl_xor; fp32 accumulate.
// Output yh ROW-major [NNODES][256] (GEMM A operand).
__global__ __launch_bounds__(256) void agg_chunk(const ushort* __restrict__ xh, ushort* __restrict__ yh,
                                                 const float* __restrict__ dis,
                                                 const int* __restrict__ offs, const int2* __restrict__ csr_pair) {
    int wave = threadIdx.x >> 6;
    int lane = threadIdx.x & 63;
    int eg = lane >> 2;                 // edge slot 0..15
    int fq = lane & 3;                  // 16B quad within the 64B chunk row
    int chunk = blockIdx.x & 7;
    int v = (blockIdx.x >> 3) * 4 + wave;   // 50000 % 4 == 0 -> always < NNODES
    int beg = offs[v], end = offs[v + 1];
    int deg = end - beg;
    float dv = dis[v];
    float sw = dv * dv;
    const _Float16* xc = (const _Float16*)xh + (size_t)chunk * NNODES * 32;

    float acc[8];
    #pragma unroll
    for (int j = 0; j < 8; ++j) acc[j] = 0.f;

    int trips = (deg + 16) >> 4;        // ceil((deg+1)/16), wave-uniform (one node per wave)
    for (int k = 0; k < trips; ++k) {
        int j = k * 16 + eg;            // logical edge: 0 = self, 1..deg = csr
        bool self = (j == 0);
        bool val = (j <= deg) && !self;
        int ic = val ? (beg + j - 1) : 0;
        int2 pr = csr_pair[ic];
        int s   = self ? v : pr.x;
        float w = self ? sw : (val ? __int_as_float(pr.y) : 0.f);
        half8 g = *(const half8*)(xc + (size_t)s * 32 + fq * 8);
        #pragma unroll
        for (int q = 0; q < 8; ++q) acc[q] += (float)g[q] * w;
    }
    #pragma unroll
    for (int m = 4; m <= 32; m <<= 1)
        #pragma unroll
        for (int q = 0; q < 8; ++q) acc[q] += __shfl_xor(acc[q], m, 64);

    if (eg == 0) {
        ushort h[8];
        #pragma unroll
        for (int q = 0; q < 8; ++q) h[q] = f2h(acc[q]);
        short8 hv = {(short)h[0], (short)h[1], (short)h[2], (short)h[3],
                     (short)h[4], (short)h[5], (short)h[6], (short)h[7]};
        *(short8*)(yh + (size_t)v * 256 + chunk * 32 + fq * 8) = hv;
    }
}

// ---------------- fused gate+pool: per graph, 16 waves (BW-bound -> max occupancy) ----------------
__global__ __launch_bounds__(1024) void gatepool(const float* __restrict__ x, const float* __restrict__ pw,
                                                 const float* __restrict__ pb, const int* __restrict__ batch,
                                                 ushort* __restrict__ phi, ushort* __restrict__ plo, int n) {
    int g = blockIdx.x;
    int t = threadIdx.x;
    int wave = t >> 6, lane = t & 63;
    int lo_ = 0, hi_ = n;
    while (lo_ < hi_) { int mid = (lo_ + hi_) >> 1; if (batch[mid] < g) lo_ = mid + 1; else hi_ = mid; }
    int start = lo_;
    hi_ = n;
    while (lo_ < hi_) { int mid = (lo_ + hi_) >> 1; if (batch[mid] < g + 1) lo_ = mid + 1; else hi_ = mid; }
    int end = lo_;

    const float4* pwv = (const float4*)pw;
    float4 wa = pwv[lane], wb = pwv[lane + 64];
    float pb0 = pb[0];

    float4 s0 = make_float4(0.f, 0.f, 0.f, 0.f), s1 = s0;
    float4 m0 = make_float4(-INFINITY, -INFINITY, -INFINITY, -INFINITY), m1 = m0;

    for (int nn = start + wave; nn < end; nn += 16) {
        const float4* xr = (const float4*)(x + (size_t)nn * 512);
        float4 a = xr[lane];
        float4 b = xr[lane + 64];
        float p = a.x * wa.x + a.y * wa.y + a.z * wa.z + a.w * wa.w
                + b.x * wb.x + b.y * wb.y + b.z * wb.z + b.w * wb.w;
        #pragma unroll
        for (int off = 32; off; off >>= 1) p += __shfl_down(p, off, 64);
        float wg = __shfl(p, 0, 64);
        wg = 1.f / (1.f + expf(-(wg + pb0)));
        s0.x += a.x * wg; s0.y += a.y * wg; s0.z += a.z * wg; s0.w += a.w * wg;
        s1.x += b.x * wg; s1.y += b.y * wg; s1.z += b.z * wg; s1.w += b.w * wg;
        m0.x = fmaxf(m0.x, a.x); m0.y = fmaxf(m0.y, a.y); m0.z = fmaxf(m0.z, a.z); m0.w = fmaxf(m0.w, a.w);
        m1.x = fmaxf(m1.x, b.x); m1.y = fmaxf(m1.y, b.y); m1.z = fmaxf(m1.z, b.z); m1.w = fmaxf(m1.w, b.w);
    }

    __shared__ float ls[16][1024];
    *(float4*)&ls[wave][lane * 4]       = s0;
    *(float4*)&ls[wave][256 + lane * 4] = s1;
    *(float4*)&ls[wave][512 + lane * 4] = m0;
    *(float4*)&ls[wave][768 + lane * 4] = m1;
    __syncthreads();

    // thread t reduces one of the 1024 output slots across 16 waves
    float val;
    if (t < 512) {
        float s = 0.f;
        #pragma unroll
        for (int wv = 0; wv < 16; ++wv) s += ls[wv][t];
        val = s;
    } else {
        float m = -INFINITY;
        #pragma unroll
        for (int wv = 0; wv < 16; ++wv) m = fmaxf(m, ls[wv][t]);
        if (start >= end) m = 0.f;
        val = m;
    }
    ushort h, l;
    split2h(val, h, l);
    size_t base = (size_t)g * 1024;
    phi[base + t] = h;
    plo[base + t] = l;
}

// ---------------- launch ----------------

extern "C" void kernel_launch(void* const* d_in, const int* in_sizes, int n_in,
                              void* d_out, int out_size, void* d_ws, size_t ws_size,
                              hipStream_t stream) {
    const float* x0    = (const float*)d_in[0];
    const int*   ei    = (const int*)d_in[1];
    const int*   batch = (const int*)d_in[2];
    const float* W1 = (const float*)d_in[3];
    const float* b1 = (const float*)d_in[4];
    const float* W2 = (const float*)d_in[5];
    const float* b2 = (const float*)d_in[6];
    const float* W3 = (const float*)d_in[7];
    const float* b3 = (const float*)d_in[8];
    const float* pw = (const float*)d_in[9];
    const float* pb = (const float*)d_in[10];
    const float* Wo = (const float*)d_in[11];
    const float* bo = (const float*)d_in[12];
    float* out = (float*)d_out;

    // workspace layout (float units, 16B-aligned regions)
    float* ws = (float*)d_ws;
    size_t off = 0;
    float* bufB = ws + off; off += (size_t)NNODES * 512;                 // x3 fp32 / head split-K partials
    ushort* xh  = (ushort*)(ws + off); off += (size_t)NNODES * 256 / 2;  // activation fp16 table (chunk-major)
    ushort* yh  = (ushort*)(ws + off); off += (size_t)NNODES * 256 / 2;  // agg out fp16 (row-major)
    int*    rank = (int*)(ws + off);   off += (size_t)NNODES * 256 / 2;  // edge ranks
    ushort* W1thi = (ushort*)(ws + off); off += 256 * 256 / 2;
    ushort* W1tlo = (ushort*)(ws + off); off += 256 * 256 / 2;
    ushort* W2thi = (ushort*)(ws + off); off += 256 * 256 / 2;
    ushort* W2tlo = (ushort*)(ws + off); off += 256 * 256 / 2;
    ushort* W3thi = (ushort*)(ws + off); off += 512 * 256 / 2;
    ushort* W3tlo = (ushort*)(ws + off); off += 512 * 256 / 2;
    ushort* Wothi = (ushort*)(ws + off); off += (size_t)FPOUT * 1024 / 2;
    ushort* Wotlo = (ushort*)(ws + off); off += (size_t)FPOUT * 1024 / 2;
    ushort* phi = (ushort*)(ws + off); off += (size_t)NGRAPH * 1024 / 2;
    ushort* plo = (ushort*)(ws + off); off += (size_t)NGRAPH * 1024 / 2;
    float* dis  = ws + off; off += NNODES;
    int*   degi = (int*)(ws + off); off += NNODES;
    int*   offs = (int*)(ws + off); off += (NNODES + 4);
    int*   curs_unused = (int*)(ws + off); off += NNODES;
    (void)curs_unused;
    int2*  csr_pair = (int2*)(ws + off); off += 2 * (size_t)NEDGES;      // packed {src, w}
    int*   partials = (int*)(ws + off); off += 256;

    const int NB_N = (NNODES + 255) / 256;   // 196
    const int NB_E = (NEDGES + 255) / 256;
    const int NB_A = (NNODES / 4) * 8;       // 100000 blocks: 4 nodes/block x 8 chunks
    const int MB128 = (NNODES + 127) / 128;  // 391

    // weight transpose+split (LDS-tiled, coalesced); layers use hi (= RNE fp16 W) only
    { dim3 g(256 / 32, 256 / 32);    wsplit_t<<<g, 256, 0, stream>>>(W1, W1thi, W1tlo, 256, 256); }
    { dim3 g(256 / 32, 256 / 32);    wsplit_t<<<g, 256, 0, stream>>>(W2, W2thi, W2tlo, 256, 256); }
    { dim3 g(512 / 32, 256 / 32);    wsplit_t<<<g, 256, 0, stream>>>(W3, W3thi, W3tlo, 256, 512); }
    { dim3 g(FPOUT / 32, 1024 / 32); wsplit_t<<<g, 256, 0, stream>>>(Wo, Wothi, Wotlo, 1024, FPOUT); }

    // CSR build (atomic-free scatter: rank captured in count_deg)
    zero_i32<<<NB_N, 256, 0, stream>>>(degi, NNODES);
    count_deg<<<NB_E, 256, 0, stream>>>(ei, degi, rank, NEDGES);
    calc_dis<<<NB_N, 256, 0, stream>>>(degi, dis, NNODES);
    scanA<<<NB_N, 256, 0, stream>>>(degi, offs, partials, NNODES);
    scanB<<<1, 256, 0, stream>>>(partials, NB_N);
    scanC<<<NB_N, 256, 0, stream>>>(offs, partials, NNODES);
    fill_csr<<<NB_E, 256, 0, stream>>>(ei, dis, offs, rank, csr_pair, NEDGES);

    // x0 -> fp16 table (chunk-major)
    conv_f16<<<(NNODES * 256 / 4 + 255) / 256, 256, 0, stream>>>(x0, xh, NNODES * 256 / 4);

    // layer 1: y = A_norm @ x0h ; x1h = fp16(relu(y @ W1 + b1)) (chunk-major)
    agg_chunk<<<NB_A, 256, 0, stream>>>(xh, yh, dis, offs, csr_pair);
    {
        dim3 grid(H1 / 128, MB128);
        gemm_f16<0, 0, 256><<<grid, 256, 0, stream>>>(yh, nullptr, W1thi, nullptr, nullptr, xh, b1,
                                                      NNODES, H1, FIN, 1, 1);
    }
    // layer 2
    agg_chunk<<<NB_A, 256, 0, stream>>>(xh, yh, dis, offs, csr_pair);
    {
        dim3 grid(H2 / 128, MB128);
        gemm_f16<0, 0, 256><<<grid, 256, 0, stream>>>(yh, nullptr, W2thi, nullptr, nullptr, xh, b2,
                                                      NNODES, H2, H1, 1, 1);
    }
    // layer 3: agg on x2h, GEMM 256->512 -> fp32 (gatepool input)
    agg_chunk<<<NB_A, 256, 0, stream>>>(xh, yh, dis, offs, csr_pair);
    {
        dim3 grid(H3 / 128, MB128);
        gemm_f16<0, 0, 256><<<grid, 256, 0, stream>>>(yh, nullptr, W3thi, nullptr, bufB, nullptr, b3,
                                                      NNODES, H3, H2, 1, 0);
    }
    // fused gate+pool -> pooled fp16 hi/lo (Dekker pairs)
    gatepool<<<NGRAPH, 1024, 0, stream>>>(bufB, pw, pb, batch, phi, plo, NNODES);
    // head: split-K over 4 z-slices into bufB partials (reused; gatepool is done with it),
    // then finish pass applies bias+relu.  3-term split-fp16 MFMA (~fp32 accurate).
    {
        dim3 grid(FPOUT / 128, (NGRAPH + 127) / 128, 4);
        gemm_f16<1, 1, 256><<<grid, 256, 0, stream>>>(phi, plo, Wothi, Wotlo, bufB, nullptr, nullptr,
                                                      NGRAPH, FPOUT, 1024, 0, 0);
    }
    head_fin<<<(NGRAPH * FPOUT / 4 + 255) / 256, 256, 0, stream>>>(bufB, bo, out);
}

// Round 6
// 732.100 us; speedup vs baseline: 1.0806x; 1.0806x over previous
//
#include <hip/hip_runtime.h>
#include <math.h>

#define NNODES 50000
#define NEDGES 800000
#define NGRAPH 512
#define FIN    256
#define H1     256
#define H2     256
#define H3     512
#define FPOUT  2048

typedef __attribute__((ext_vector_type(8))) short short8;
typedef __attribute__((ext_vector_type(8))) _Float16 half8;
typedef __attribute__((ext_vector_type(4))) float floatx4;
typedef __attribute__((ext_vector_type(4))) unsigned short ushx4;

// fp16 helpers: v_cvt_f16_f32 is RNE on gfx950
__device__ inline float h2f(ushort u) { return (float)__builtin_bit_cast(_Float16, u); }
__device__ inline ushort f2h(float x) { return __builtin_bit_cast(ushort, (_Float16)x); }
// Dekker split: a = hi + lo with hi = RNE-fp16(a); lo carries ~11 more mantissa bits.
__device__ inline void split2h(float a, ushort& h, ushort& l) {
    _Float16 hh = (_Float16)a;
    h = __builtin_bit_cast(ushort, hh);
    l = f2h(a - (float)hh);
}

// ---------------- utility kernels ----------------

__global__ __launch_bounds__(256) void zero_i32(int* p, int n) {
    int i = blockIdx.x * 256 + threadIdx.x;
    if (i < n) p[i] = 0;
}

// count degrees AND record each edge's rank within its destination (atomic returns old)
__global__ __launch_bounds__(256) void count_deg(const int* __restrict__ ei, int* __restrict__ degi,
                                                 int* __restrict__ rank, int e_total) {
    int e = blockIdx.x * 256 + threadIdx.x;
    if (e >= e_total) return;
    int d = ei[e_total + e];
    rank[e] = atomicAdd(&degi[d], 1);
}

__global__ __launch_bounds__(256) void calc_dis(const int* __restrict__ degi, float* __restrict__ dis, int n) {
    int i = blockIdx.x * 256 + threadIdx.x;
    if (i < n) dis[i] = rsqrtf((float)(degi[i] + 1));   // +1 self loop
}

__global__ __launch_bounds__(256) void scanA(const int* __restrict__ degi, int* __restrict__ offs,
                                             int* __restrict__ partials, int n) {
    __shared__ int sm[256];
    int t = threadIdx.x, idx = blockIdx.x * 256 + t;
    int v = (idx < n) ? degi[idx] : 0;
    sm[t] = v; __syncthreads();
    for (int d = 1; d < 256; d <<= 1) {
        int add = (t >= d) ? sm[t - d] : 0;
        __syncthreads();
        sm[t] += add;
        __syncthreads();
    }
    if (idx < n) offs[idx + 1] = sm[t];
    if (t == 255) partials[blockIdx.x] = sm[255];
}

__global__ __launch_bounds__(256) void scanB(int* __restrict__ partials, int nb) {
    __shared__ int sm[256];
    int t = threadIdx.x;
    int v = (t < nb) ? partials[t] : 0;
    sm[t] = v; __syncthreads();
    for (int d = 1; d < 256; d <<= 1) {
        int add = (t >= d) ? sm[t - d] : 0;
        __syncthreads();
        sm[t] += add;
        __syncthreads();
    }
    if (t < nb) partials[t] = sm[t] - v;   // exclusive
}

__global__ __launch_bounds__(256) void scanC(int* __restrict__ offs, const int* __restrict__ partials, int n) {
    int idx = blockIdx.x * 256 + threadIdx.x;
    if (idx < n) offs[idx + 1] += partials[blockIdx.x];
    if (idx == 0) offs[0] = 0;
}

// atomic-free scatter: pos = offs[d] + rank[e]; one packed 8B store per edge
__global__ __launch_bounds__(256) void fill_csr(const int* __restrict__ ei, const float* __restrict__ dis,
                                                const int* __restrict__ offs, const int* __restrict__ rank,
                                                int2* __restrict__ csr_pair, int e_total) {
    int e = blockIdx.x * 256 + threadIdx.x;
    if (e >= e_total) return;
    int s = ei[e];
    int d = ei[e_total + e];
    int pos = offs[d] + rank[e];
    int2 pr;
    pr.x = s;
    pr.y = __float_as_int(dis[s] * dis[d]);
    csr_pair[pos] = pr;
}

// W[K][N] fp32 -> Wt_hi[N][K], Wt_lo[N][K] (fp16 Dekker pair): LDS-tiled transpose
__global__ __launch_bounds__(256) void wsplit_t(const float* __restrict__ W, ushort* __restrict__ hi,
                                                ushort* __restrict__ lo, int K, int N) {
    __shared__ float sm[32][33];
    int tx = threadIdx.x & 31, ty = threadIdx.x >> 5;   // 32 x 8
    int n0 = blockIdx.x * 32, k0 = blockIdx.y * 32;
    #pragma unroll
    for (int j = 0; j < 32; j += 8)
        sm[ty + j][tx] = W[(size_t)(k0 + ty + j) * N + n0 + tx];
    __syncthreads();
    #pragma unroll
    for (int j = 0; j < 32; j += 8) {
        float a = sm[tx][ty + j];
        ushort h, l; split2h(a, h, l);
        size_t o = (size_t)(n0 + ty + j) * K + k0 + tx;
        hi[o] = h; lo[o] = l;
    }
}

// x fp32 -> fp16 table, CHUNK-MAJOR layout [8][NNODES][32]:
// element (node n, feat f) -> xh[((f>>5)*NNODES + n)*32 + (f&31)]
__global__ __launch_bounds__(256) void conv_f16(const float* __restrict__ x, ushort* __restrict__ xh, int total4) {
    int i = blockIdx.x * 256 + threadIdx.x;
    if (i >= total4) return;
    int n  = i >> 6;          // node
    int f4 = i & 63;          // float-quad within row (f = f4*4)
    float4 a = ((const float4*)x)[i];
    ushx4 h = {f2h(a.x), f2h(a.y), f2h(a.z), f2h(a.w)};
    size_t o4 = (((size_t)(f4 >> 3) * NNODES + n) * 32 + (f4 & 7) * 4) >> 2;  // ushx4 index
    ((ushx4*)xh)[o4] = h;
}

// ---------------- MFMA fp16 GEMM: BK=64, XOR-swizzled LDS, XCD-chunked blocks ----------------
// SPLIT=0: C = relu(A @ B^T + bias), single fp16 operands, 1 MFMA per frag pair.
// SPLIT=1: fp16 Dekker pairs, 3 MFMAs: Ah*Bh + Ah*Bl + Al*Bh (~fp32-accurate). Head GEMM.
// ACC=1: store raw acc to partial buffer C + z*M*N (split-K, finish kernel applies bias/relu).
// outmode 1: write fp16 activation table in CHUNK-MAJOR [N/32][M][32] layout.
// KSPAN: compile-time K-range per z-slice. K = runtime row stride.
template<int SPLIT, int ACC, int KSPAN>
__global__ __launch_bounds__(256) void gemm_f16(const ushort* __restrict__ Ahp, const ushort* __restrict__ Alp,
                                                const ushort* __restrict__ Bhp, const ushort* __restrict__ Blp,
                                                float* __restrict__ C, ushort* __restrict__ Ch,
                                                const float* __restrict__ bias,
                                                int M, int N, int K, int do_relu, int outmode) {
    __shared__ _Float16 lsA[128 * 64];
    __shared__ _Float16 lsB[128 * 64];
    __shared__ _Float16 lsAl[SPLIT ? 128 * 64 : 8];
    __shared__ _Float16 lsBl[SPLIT ? 128 * 64 : 8];
    const _Float16* Ah = (const _Float16*)Ahp;
    const _Float16* Al = (const _Float16*)Alp;
    const _Float16* Bh = (const _Float16*)Bhp;
    const _Float16* Bl = (const _Float16*)Blp;

    int tid = threadIdx.x;
    int w = tid >> 6, lane = tid & 63;
    int quad = lane >> 4, lr = lane & 15;
    int wm = w & 1, wn = w >> 1;

    // bijective XCD-chunked swizzle (m204): same row-panel's col-tiles land on one XCD
    int gx = gridDim.x;
    int orig = blockIdx.y * gx + blockIdx.x;
    int nwg = gx * gridDim.y;
    int xcd = orig & 7, slot = orig >> 3;
    int q = nwg >> 3, r = nwg & 7;
    int wid = (xcd < r ? xcd * (q + 1) : r * (q + 1) + (xcd - r) * q) + slot;
    int row0 = (wid / gx) * 128, col0 = (wid % gx) * 128;
    int kb = blockIdx.z * KSPAN;

    floatx4 acc[4][4];
    #pragma unroll
    for (int i = 0; i < 4; ++i)
        #pragma unroll
        for (int j = 0; j < 4; ++j)
            acc[i][j] = (floatx4){0.f, 0.f, 0.f, 0.f};

    const half8 zer = {};
    int srow = tid >> 3;                         // 0..31 (chunk adds +32)
    int sgran = tid & 7;                         // logical 16B granule within BK=64
    int skk = sgran * 8;                         // logical k offset (halves)
    int sgx = (sgran ^ (srow & 7)) * 8;          // swizzled LDS granule offset (halves)

    half8 pa[4], pb[4], pal[4], pbl[4];
    // prologue: load k-step 0
    #pragma unroll
    for (int c = 0; c < 4; ++c) {
        int row = c * 32 + srow;
        bool mok = (row0 + row) < M;
        size_t aoff = (size_t)(row0 + row) * K + kb + skk;
        pa[c] = mok ? *(const half8*)(Ah + aoff) : zer;
        if constexpr (SPLIT) pal[c] = mok ? *(const half8*)(Al + aoff) : zer;
        size_t boff = (size_t)(col0 + row) * K + kb + skk;
        pb[c] = *(const half8*)(Bh + boff);
        if constexpr (SPLIT) pbl[c] = *(const half8*)(Bl + boff);
    }

    for (int k0 = kb; k0 < kb + KSPAN; k0 += 64) {
        // commit prefetched step to LDS (swizzled granule)
        #pragma unroll
        for (int c = 0; c < 4; ++c) {
            int lo = (c * 32 + srow) * 64 + sgx;
            *(half8*)(lsA + lo) = pa[c];
            *(half8*)(lsB + lo) = pb[c];
            if constexpr (SPLIT) { *(half8*)(lsAl + lo) = pal[c]; *(half8*)(lsBl + lo) = pbl[c]; }
        }
        __syncthreads();
        // issue next step's global loads — overlap with the MFMA section below
        if (k0 + 64 < kb + KSPAN) {
            #pragma unroll
            for (int c = 0; c < 4; ++c) {
                int row = c * 32 + srow;
                bool mok = (row0 + row) < M;
                size_t aoff = (size_t)(row0 + row) * K + k0 + 64 + skk;
                pa[c] = mok ? *(const half8*)(Ah + aoff) : zer;
                if constexpr (SPLIT) pal[c] = mok ? *(const half8*)(Al + aoff) : zer;
                size_t boff = (size_t)(col0 + row) * K + k0 + 64 + skk;
                pb[c] = *(const half8*)(Bh + boff);
                if constexpr (SPLIT) pbl[c] = *(const half8*)(Bl + boff);
            }
        }
        #pragma unroll
        for (int kk = 0; kk < 2; ++kk) {
            half8 af[4], afl[4];
            #pragma unroll
            for (int mt = 0; mt < 4; ++mt) {
                int row = wm * 64 + mt * 16 + lr;
                int ao = row * 64 + (((kk * 4 + quad) ^ (row & 7)) << 3);
                af[mt] = *(const half8*)(lsA + ao);
                if constexpr (SPLIT) afl[mt] = *(const half8*)(lsAl + ao);
            }
            #pragma unroll
            for (int nt = 0; nt < 4; ++nt) {
                int row = wn * 64 + nt * 16 + lr;
                int bo = row * 64 + (((kk * 4 + quad) ^ (row & 7)) << 3);
                half8 bf = *(const half8*)(lsB + bo);
                half8 bfl;
                if constexpr (SPLIT) bfl = *(const half8*)(lsBl + bo);
                #pragma unroll
                for (int mt = 0; mt < 4; ++mt) {
                    acc[mt][nt] = __builtin_amdgcn_mfma_f32_16x16x32_f16(af[mt], bf, acc[mt][nt], 0, 0, 0);
                    if constexpr (SPLIT) {
                        acc[mt][nt] = __builtin_amdgcn_mfma_f32_16x16x32_f16(af[mt], bfl, acc[mt][nt], 0, 0, 0);
                        acc[mt][nt] = __builtin_amdgcn_mfma_f32_16x16x32_f16(afl[mt], bf, acc[mt][nt], 0, 0, 0);
                    }
                }
            }
        }
        __syncthreads();
    }

    size_t zoff = ACC ? (size_t)blockIdx.z * M * N : 0;
    #pragma unroll
    for (int mt = 0; mt < 4; ++mt) {
        #pragma unroll
        for (int rr = 0; rr < 4; ++rr) {
            int row = row0 + wm * 64 + mt * 16 + quad * 4 + rr;
            if (row >= M) continue;
            #pragma unroll
            for (int nt = 0; nt < 4; ++nt) {
                int col = col0 + wn * 64 + nt * 16 + lr;
                float v = acc[mt][nt][rr];
                if (!ACC) {
                    v += bias[col];
                    if (do_relu) v = v > 0.f ? v : 0.f;
                }
                if (outmode) Ch[((size_t)(col >> 5) * M + row) * 32 + (col & 31)] = f2h(v);
                else         C[zoff + (size_t)row * N + col] = v;
            }
        }
    }
}

// finish for split-K head: out = relu(sum_z partials + bias), vectorized float4
__global__ __launch_bounds__(256) void head_fin(const float* __restrict__ part, const float* __restrict__ bo,
                                                float* __restrict__ out) {
    int i4 = blockIdx.x * 256 + threadIdx.x;          // element-quad index
    const int TOT4 = NGRAPH * FPOUT / 4;
    if (i4 >= TOT4) return;
    int col4 = i4 & (FPOUT / 4 - 1);
    const size_t STRIDE4 = (size_t)NGRAPH * FPOUT / 4;
    const float4* p = (const float4*)part;
    float4 a = p[i4];
    float4 b = p[i4 + STRIDE4];
    float4 c = p[i4 + 2 * STRIDE4];
    float4 d = p[i4 + 3 * STRIDE4];
    float4 bb = ((const float4*)bo)[col4];
    float4 o;
    o.x = a.x + b.x + c.x + d.x + bb.x; o.x = o.x > 0.f ? o.x : 0.f;
    o.y = a.y + b.y + c.y + d.y + bb.y; o.y = o.y > 0.f ? o.y : 0.f;
    o.z = a.z + b.z + c.z + d.z + bb.z; o.z = o.z > 0.f ? o.z : 0.f;
    o.w = a.w + b.w + c.w + d.w + bb.w; o.w = o.w > 0.f ? o.w : 0.f;
    ((float4*)out)[i4] = o;
}

// ---------------- aggregation: feature-chunked, dense 16-nodes-per-wave ----------------
// xh chunk-major [8][NNODES][32]. chunk = blockIdx.y; x-major dispatch processes one
// 3.2 MB slice chip-wide at a time -> slice is L2-resident on every XCD.
// Wave: node = lane>>2 (16 nodes), quad = lane&3 (16B feature slot). Lane-local fp32
// accumulators (no reduce shuffles); per trip each node advances one edge; trips =
// wave-max degree (4-step shfl_xor max). All 64 lanes gather (1KB/instr) and write.
// Inner MAC compiles to v_fma_mix_f32 ((float)fp16 * fp32). Bit-identical to the
// row-major agg (same edge order, fp32 w, fp32 accum, fp16 store).
__global__ __launch_bounds__(256) void agg_chunk(const ushort* __restrict__ xh, ushort* __restrict__ yh,
                                                 const float* __restrict__ dis,
                                                 const int* __restrict__ offs, const int2* __restrict__ csr_pair) {
    int wave = threadIdx.x >> 6;
    int lane = threadIdx.x & 63;
    int nd   = lane >> 2;               // node slot 0..15
    int quad = lane & 3;                // 16B quad within the 64B chunk row
    int chunk = blockIdx.y;
    int v = blockIdx.x * 64 + wave * 16 + nd;
    bool vok = v < NNODES;
    int vv = vok ? v : 0;
    int beg = offs[vv], end = offs[vv + 1];
    int deg = vok ? (end - beg) : 0;
    float dv = dis[vv];
    float sw = dv * dv;
    const _Float16* xc = (const _Float16*)xh + (size_t)chunk * NNODES * 32;

    // self-loop contribution
    half8 a0 = *(const half8*)(xc + (size_t)vv * 32 + quad * 8);
    float acc[8];
    #pragma unroll
    for (int j = 0; j < 8; ++j) acc[j] = (float)a0[j] * sw;

    // wave-max degree over the 16 node groups (quad bits untouched)
    int md = deg;
    #pragma unroll
    for (int m = 4; m <= 32; m <<= 1) {
        int o = __shfl_xor(md, m, 64);
        md = md > o ? md : o;
    }

    for (int t = 0; t < md; ++t) {
        bool val = t < deg;
        int ic = val ? beg + t : 0;
        int2 pr = csr_pair[ic];
        int s   = val ? pr.x : 0;
        float w = val ? __int_as_float(pr.y) : 0.f;
        half8 g = *(const half8*)(xc + (size_t)s * 32 + quad * 8);
        #pragma unroll
        for (int j = 0; j < 8; ++j) acc[j] += (float)g[j] * w;
    }

    if (vok) {
        ushort h[8];
        #pragma unroll
        for (int j = 0; j < 8; ++j) h[j] = f2h(acc[j]);
        short8 hv = {(short)h[0], (short)h[1], (short)h[2], (short)h[3],
                     (short)h[4], (short)h[5], (short)h[6], (short)h[7]};
        *(short8*)(yh + (size_t)v * 256 + chunk * 32 + quad * 8) = hv;
    }
}

// ---------------- fused gate+pool: per graph, 16 waves (BW-bound -> max occupancy) ----------------
__global__ __launch_bounds__(1024) void gatepool(const float* __restrict__ x, const float* __restrict__ pw,
                                                 const float* __restrict__ pb, const int* __restrict__ batch,
                                                 ushort* __restrict__ phi, ushort* __restrict__ plo, int n) {
    int g = blockIdx.x;
    int t = threadIdx.x;
    int wave = t >> 6, lane = t & 63;
    int lo_ = 0, hi_ = n;
    while (lo_ < hi_) { int mid = (lo_ + hi_) >> 1; if (batch[mid] < g) lo_ = mid + 1; else hi_ = mid; }
    int start = lo_;
    hi_ = n;
    while (lo_ < hi_) { int mid = (lo_ + hi_) >> 1; if (batch[mid] < g + 1) lo_ = mid + 1; else hi_ = mid; }
    int end = lo_;

    const float4* pwv = (const float4*)pw;
    float4 wa = pwv[lane], wb = pwv[lane + 64];
    float pb0 = pb[0];

    float4 s0 = make_float4(0.f, 0.f, 0.f, 0.f), s1 = s0;
    float4 m0 = make_float4(-INFINITY, -INFINITY, -INFINITY, -INFINITY), m1 = m0;

    for (int nn = start + wave; nn < end; nn += 16) {
        const float4* xr = (const float4*)(x + (size_t)nn * 512);
        float4 a = xr[lane];
        float4 b = xr[lane + 64];
        float p = a.x * wa.x + a.y * wa.y + a.z * wa.z + a.w * wa.w
                + b.x * wb.x + b.y * wb.y + b.z * wb.z + b.w * wb.w;
        #pragma unroll
        for (int off = 32; off; off >>= 1) p += __shfl_down(p, off, 64);
        float wg = __shfl(p, 0, 64);
        wg = 1.f / (1.f + expf(-(wg + pb0)));
        s0.x += a.x * wg; s0.y += a.y * wg; s0.z += a.z * wg; s0.w += a.w * wg;
        s1.x += b.x * wg; s1.y += b.y * wg; s1.z += b.z * wg; s1.w += b.w * wg;
        m0.x = fmaxf(m0.x, a.x); m0.y = fmaxf(m0.y, a.y); m0.z = fmaxf(m0.z, a.z); m0.w = fmaxf(m0.w, a.w);
        m1.x = fmaxf(m1.x, b.x); m1.y = fmaxf(m1.y, b.y); m1.z = fmaxf(m1.z, b.z); m1.w = fmaxf(m1.w, b.w);
    }

    __shared__ float ls[16][1024];
    *(float4*)&ls[wave][lane * 4]       = s0;
    *(float4*)&ls[wave][256 + lane * 4] = s1;
    *(float4*)&ls[wave][512 + lane * 4] = m0;
    *(float4*)&ls[wave][768 + lane * 4] = m1;
    __syncthreads();

    // thread t reduces one of the 1024 output slots across 16 waves
    float val;
    if (t < 512) {
        float s = 0.f;
        #pragma unroll
        for (int wv = 0; wv < 16; ++wv) s += ls[wv][t];
        val = s;
    } else {
        float m = -INFINITY;
        #pragma unroll
        for (int wv = 0; wv < 16; ++wv) m = fmaxf(m, ls[wv][t]);
        if (start >= end) m = 0.f;
        val = m;
    }
    ushort h, l;
    split2h(val, h, l);
    size_t base = (size_t)g * 1024;
    phi[base + t] = h;
    plo[base + t] = l;
}

// ---------------- launch ----------------

extern "C" void kernel_launch(void* const* d_in, const int* in_sizes, int n_in,
                              void* d_out, int out_size, void* d_ws, size_t ws_size,
                              hipStream_t stream) {
    const float* x0    = (const float*)d_in[0];
    const int*   ei    = (const int*)d_in[1];
    const int*   batch = (const int*)d_in[2];
    const float* W1 = (const float*)d_in[3];
    const float* b1 = (const float*)d_in[4];
    const float* W2 = (const float*)d_in[5];
    const float* b2 = (const float*)d_in[6];
    const float* W3 = (const float*)d_in[7];
    const float* b3 = (const float*)d_in[8];
    const float* pw = (const float*)d_in[9];
    const float* pb = (const float*)d_in[10];
    const float* Wo = (const float*)d_in[11];
    const float* bo = (const float*)d_in[12];
    float* out = (float*)d_out;

    // workspace layout (float units, 16B-aligned regions)
    float* ws = (float*)d_ws;
    size_t off = 0;
    float* bufB = ws + off; off += (size_t)NNODES * 512;                 // x3 fp32 / head split-K partials
    ushort* xh  = (ushort*)(ws + off); off += (size_t)NNODES * 256 / 2;  // activation fp16 table (chunk-major)
    ushort* yh  = (ushort*)(ws + off); off += (size_t)NNODES * 256 / 2;  // agg out fp16 (row-major)
    int*    rank = (int*)(ws + off);   off += (size_t)NNODES * 256 / 2;  // edge ranks
    ushort* W1thi = (ushort*)(ws + off); off += 256 * 256 / 2;
    ushort* W1tlo = (ushort*)(ws + off); off += 256 * 256 / 2;
    ushort* W2thi = (ushort*)(ws + off); off += 256 * 256 / 2;
    ushort* W2tlo = (ushort*)(ws + off); off += 256 * 256 / 2;
    ushort* W3thi = (ushort*)(ws + off); off += 512 * 256 / 2;
    ushort* W3tlo = (ushort*)(ws + off); off += 512 * 256 / 2;
    ushort* Wothi = (ushort*)(ws + off); off += (size_t)FPOUT * 1024 / 2;
    ushort* Wotlo = (ushort*)(ws + off); off += (size_t)FPOUT * 1024 / 2;
    ushort* phi = (ushort*)(ws + off); off += (size_t)NGRAPH * 1024 / 2;
    ushort* plo = (ushort*)(ws + off); off += (size_t)NGRAPH * 1024 / 2;
    float* dis  = ws + off; off += NNODES;
    int*   degi = (int*)(ws + off); off += NNODES;
    int*   offs = (int*)(ws + off); off += (NNODES + 4);
    int*   curs_unused = (int*)(ws + off); off += NNODES;
    (void)curs_unused;
    int2*  csr_pair = (int2*)(ws + off); off += 2 * (size_t)NEDGES;      // packed {src, w}
    int*   partials = (int*)(ws + off); off += 256;

    const int NB_N = (NNODES + 255) / 256;   // 196
    const int NB_E = (NEDGES + 255) / 256;
    const int MB128 = (NNODES + 127) / 128;  // 391

    // weight transpose+split (LDS-tiled, coalesced); layers use hi (= RNE fp16 W) only
    { dim3 g(256 / 32, 256 / 32);    wsplit_t<<<g, 256, 0, stream>>>(W1, W1thi, W1tlo, 256, 256); }
    { dim3 g(256 / 32, 256 / 32);    wsplit_t<<<g, 256, 0, stream>>>(W2, W2thi, W2tlo, 256, 256); }
    { dim3 g(512 / 32, 256 / 32);    wsplit_t<<<g, 256, 0, stream>>>(W3, W3thi, W3tlo, 256, 512); }
    { dim3 g(FPOUT / 32, 1024 / 32); wsplit_t<<<g, 256, 0, stream>>>(Wo, Wothi, Wotlo, 1024, FPOUT); }

    // CSR build (atomic-free scatter: rank captured in count_deg)
    zero_i32<<<NB_N, 256, 0, stream>>>(degi, NNODES);
    count_deg<<<NB_E, 256, 0, stream>>>(ei, degi, rank, NEDGES);
    calc_dis<<<NB_N, 256, 0, stream>>>(degi, dis, NNODES);
    scanA<<<NB_N, 256, 0, stream>>>(degi, offs, partials, NNODES);
    scanB<<<1, 256, 0, stream>>>(partials, NB_N);
    scanC<<<NB_N, 256, 0, stream>>>(offs, partials, NNODES);
    fill_csr<<<NB_E, 256, 0, stream>>>(ei, dis, offs, rank, csr_pair, NEDGES);

    // x0 -> fp16 table (chunk-major)
    conv_f16<<<(NNODES * 256 / 4 + 255) / 256, 256, 0, stream>>>(x0, xh, NNODES * 256 / 4);

    // agg grid: x = node groups of 64 (50000 -> 782), y = chunk (x-major dispatch
    // processes one L2-resident slice at a time)
    dim3 agrid((NNODES + 63) / 64, 8);

    // layer 1: y = A_norm @ x0h ; x1h = fp16(relu(y @ W1 + b1)) (chunk-major)
    agg_chunk<<<agrid, 256, 0, stream>>>(xh, yh, dis, offs, csr_pair);
    {
        dim3 grid(H1 / 128, MB128);
        gemm_f16<0, 0, 256><<<grid, 256, 0, stream>>>(yh, nullptr, W1thi, nullptr, nullptr, xh, b1,
                                                      NNODES, H1, FIN, 1, 1);
    }
    // layer 2
    agg_chunk<<<agrid, 256, 0, stream>>>(xh, yh, dis, offs, csr_pair);
    {
        dim3 grid(H2 / 128, MB128);
        gemm_f16<0, 0, 256><<<grid, 256, 0, stream>>>(yh, nullptr, W2thi, nullptr, nullptr, xh, b2,
                                                      NNODES, H2, H1, 1, 1);
    }
    // layer 3: agg on x2h, GEMM 256->512 -> fp32 (gatepool input)
    agg_chunk<<<agrid, 256, 0, stream>>>(xh, yh, dis, offs, csr_pair);
    {
        dim3 grid(H3 / 128, MB128);
        gemm_f16<0, 0, 256><<<grid, 256, 0, stream>>>(yh, nullptr, W3thi, nullptr, bufB, nullptr, b3,
                                                      NNODES, H3, H2, 1, 0);
    }
    // fused gate+pool -> pooled fp16 hi/lo (Dekker pairs)
    gatepool<<<NGRAPH, 1024, 0, stream>>>(bufB, pw, pb, batch, phi, plo, NNODES);
    // head: split-K over 4 z-slices into bufB partials (reused; gatepool is done with it),
    // then finish pass applies bias+relu.  3-term split-fp16 MFMA (~fp32 accurate).
    {
        dim3 grid(FPOUT / 128, (NGRAPH + 127) / 128, 4);
        gemm_f16<1, 1, 256><<<grid, 256, 0, stream>>>(phi, plo, Wothi, Wotlo, bufB, nullptr, nullptr,
                                                      NGRAPH, FPOUT, 1024, 0, 0);
    }
    head_fin<<<(NGRAPH * FPOUT / 4 + 255) / 256, 256, 0, stream>>>(bufB, bo, out);
}

// Round 7
// 630.594 us; speedup vs baseline: 1.2546x; 1.1610x over previous
//
#include <hip/hip_runtime.h>
#include <math.h>

#define NNODES 50000
#define NEDGES 800000
#define NGRAPH 512
#define FIN    256
#define H1     256
#define H2     256
#define H3     512
#define FPOUT  2048

typedef __attribute__((ext_vector_type(8))) short short8;
typedef __attribute__((ext_vector_type(8))) _Float16 half8;
typedef __attribute__((ext_vector_type(4))) float floatx4;
typedef __attribute__((ext_vector_type(4))) unsigned short ushx4;

// fp16 helpers: v_cvt_f16_f32 is RNE on gfx950
__device__ inline float h2f(ushort u) { return (float)__builtin_bit_cast(_Float16, u); }
__device__ inline ushort f2h(float x) { return __builtin_bit_cast(ushort, (_Float16)x); }
// Dekker split: a = hi + lo with hi = RNE-fp16(a); lo carries ~11 more mantissa bits.
__device__ inline void split2h(float a, ushort& h, ushort& l) {
    _Float16 hh = (_Float16)a;
    h = __builtin_bit_cast(ushort, hh);
    l = f2h(a - (float)hh);
}

// ---------------- utility kernels ----------------

__global__ __launch_bounds__(256) void zero_i32(int* p, int n) {
    int i = blockIdx.x * 256 + threadIdx.x;
    if (i < n) p[i] = 0;
}

// count degrees AND record each edge's rank within its destination (atomic returns old)
__global__ __launch_bounds__(256) void count_deg(const int* __restrict__ ei, int* __restrict__ degi,
                                                 int* __restrict__ rank, int e_total) {
    int e = blockIdx.x * 256 + threadIdx.x;
    if (e >= e_total) return;
    int d = ei[e_total + e];
    rank[e] = atomicAdd(&degi[d], 1);
}

__global__ __launch_bounds__(256) void calc_dis(const int* __restrict__ degi, float* __restrict__ dis, int n) {
    int i = blockIdx.x * 256 + threadIdx.x;
    if (i < n) dis[i] = rsqrtf((float)(degi[i] + 1));   // +1 self loop
}

__global__ __launch_bounds__(256) void scanA(const int* __restrict__ degi, int* __restrict__ offs,
                                             int* __restrict__ partials, int n) {
    __shared__ int sm[256];
    int t = threadIdx.x, idx = blockIdx.x * 256 + t;
    int v = (idx < n) ? degi[idx] : 0;
    sm[t] = v; __syncthreads();
    for (int d = 1; d < 256; d <<= 1) {
        int add = (t >= d) ? sm[t - d] : 0;
        __syncthreads();
        sm[t] += add;
        __syncthreads();
    }
    if (idx < n) offs[idx + 1] = sm[t];
    if (t == 255) partials[blockIdx.x] = sm[255];
}

__global__ __launch_bounds__(256) void scanB(int* __restrict__ partials, int nb) {
    __shared__ int sm[256];
    int t = threadIdx.x;
    int v = (t < nb) ? partials[t] : 0;
    sm[t] = v; __syncthreads();
    for (int d = 1; d < 256; d <<= 1) {
        int add = (t >= d) ? sm[t - d] : 0;
        __syncthreads();
        sm[t] += add;
        __syncthreads();
    }
    if (t < nb) partials[t] = sm[t] - v;   // exclusive
}

__global__ __launch_bounds__(256) void scanC(int* __restrict__ offs, const int* __restrict__ partials, int n) {
    int idx = blockIdx.x * 256 + threadIdx.x;
    if (idx < n) offs[idx + 1] += partials[blockIdx.x];
    if (idx == 0) offs[0] = 0;
}

// atomic-free scatter: pos = offs[d] + rank[e]; one packed 8B store per edge
__global__ __launch_bounds__(256) void fill_csr(const int* __restrict__ ei, const float* __restrict__ dis,
                                                const int* __restrict__ offs, const int* __restrict__ rank,
                                                int2* __restrict__ csr_pair, int e_total) {
    int e = blockIdx.x * 256 + threadIdx.x;
    if (e >= e_total) return;
    int s = ei[e];
    int d = ei[e_total + e];
    int pos = offs[d] + rank[e];
    int2 pr;
    pr.x = s;
    pr.y = __float_as_int(dis[s] * dis[d]);
    csr_pair[pos] = pr;
}

// W[K][N] fp32 -> Wt_hi[N][K], Wt_lo[N][K] (fp16 Dekker pair): LDS-tiled transpose
__global__ __launch_bounds__(256) void wsplit_t(const float* __restrict__ W, ushort* __restrict__ hi,
                                                ushort* __restrict__ lo, int K, int N) {
    __shared__ float sm[32][33];
    int tx = threadIdx.x & 31, ty = threadIdx.x >> 5;   // 32 x 8
    int n0 = blockIdx.x * 32, k0 = blockIdx.y * 32;
    #pragma unroll
    for (int j = 0; j < 32; j += 8)
        sm[ty + j][tx] = W[(size_t)(k0 + ty + j) * N + n0 + tx];
    __syncthreads();
    #pragma unroll
    for (int j = 0; j < 32; j += 8) {
        float a = sm[tx][ty + j];
        ushort h, l; split2h(a, h, l);
        size_t o = (size_t)(n0 + ty + j) * K + k0 + tx;
        hi[o] = h; lo[o] = l;
    }
}

// x fp32 -> fp16 table, CHUNK-MAJOR layout [8][NNODES][32]:
// element (node n, feat f) -> xh[((f>>5)*NNODES + n)*32 + (f&31)]
__global__ __launch_bounds__(256) void conv_f16(const float* __restrict__ x, ushort* __restrict__ xh, int total4) {
    int i = blockIdx.x * 256 + threadIdx.x;
    if (i >= total4) return;
    int n  = i >> 6;          // node
    int f4 = i & 63;          // float-quad within row (f = f4*4)
    float4 a = ((const float4*)x)[i];
    ushx4 h = {f2h(a.x), f2h(a.y), f2h(a.z), f2h(a.w)};
    size_t o4 = (((size_t)(f4 >> 3) * NNODES + n) * 32 + (f4 & 7) * 4) >> 2;  // ushx4 index
    ((ushx4*)xh)[o4] = h;
}

// ---------------- MFMA fp16 GEMM: BK=64, XOR-swizzled LDS, XCD-chunked blocks ----------------
// SPLIT=0: C = relu(A @ B^T + bias), single fp16 operands, 1 MFMA per frag pair.
// SPLIT=1: fp16 Dekker pairs, 3 MFMAs: Ah*Bh + Ah*Bl + Al*Bh (~fp32-accurate). Head GEMM.
// ACC=1: store raw acc to partial buffer C + z*M*N (split-K, finish kernel applies bias/relu).
// outmode 1: write fp16 activation table in CHUNK-MAJOR [N/32][M][32] layout.
// KSPAN: compile-time K-range per z-slice. K = runtime row stride.
template<int SPLIT, int ACC, int KSPAN>
__global__ __launch_bounds__(256) void gemm_f16(const ushort* __restrict__ Ahp, const ushort* __restrict__ Alp,
                                                const ushort* __restrict__ Bhp, const ushort* __restrict__ Blp,
                                                float* __restrict__ C, ushort* __restrict__ Ch,
                                                const float* __restrict__ bias,
                                                int M, int N, int K, int do_relu, int outmode) {
    __shared__ _Float16 lsA[128 * 64];
    __shared__ _Float16 lsB[128 * 64];
    __shared__ _Float16 lsAl[SPLIT ? 128 * 64 : 8];
    __shared__ _Float16 lsBl[SPLIT ? 128 * 64 : 8];
    const _Float16* Ah = (const _Float16*)Ahp;
    const _Float16* Al = (const _Float16*)Alp;
    const _Float16* Bh = (const _Float16*)Bhp;
    const _Float16* Bl = (const _Float16*)Blp;

    int tid = threadIdx.x;
    int w = tid >> 6, lane = tid & 63;
    int quad = lane >> 4, lr = lane & 15;
    int wm = w & 1, wn = w >> 1;

    // bijective XCD-chunked swizzle (m204): same row-panel's col-tiles land on one XCD
    int gx = gridDim.x;
    int orig = blockIdx.y * gx + blockIdx.x;
    int nwg = gx * gridDim.y;
    int xcd = orig & 7, slot = orig >> 3;
    int q = nwg >> 3, r = nwg & 7;
    int wid = (xcd < r ? xcd * (q + 1) : r * (q + 1) + (xcd - r) * q) + slot;
    int row0 = (wid / gx) * 128, col0 = (wid % gx) * 128;
    int kb = blockIdx.z * KSPAN;

    floatx4 acc[4][4];
    #pragma unroll
    for (int i = 0; i < 4; ++i)
        #pragma unroll
        for (int j = 0; j < 4; ++j)
            acc[i][j] = (floatx4){0.f, 0.f, 0.f, 0.f};

    const half8 zer = {};
    int srow = tid >> 3;                         // 0..31 (chunk adds +32)
    int sgran = tid & 7;                         // logical 16B granule within BK=64
    int skk = sgran * 8;                         // logical k offset (halves)
    int sgx = (sgran ^ (srow & 7)) * 8;          // swizzled LDS granule offset (halves)

    half8 pa[4], pb[4], pal[4], pbl[4];
    // prologue: load k-step 0
    #pragma unroll
    for (int c = 0; c < 4; ++c) {
        int row = c * 32 + srow;
        bool mok = (row0 + row) < M;
        size_t aoff = (size_t)(row0 + row) * K + kb + skk;
        pa[c] = mok ? *(const half8*)(Ah + aoff) : zer;
        if constexpr (SPLIT) pal[c] = mok ? *(const half8*)(Al + aoff) : zer;
        size_t boff = (size_t)(col0 + row) * K + kb + skk;
        pb[c] = *(const half8*)(Bh + boff);
        if constexpr (SPLIT) pbl[c] = *(const half8*)(Bl + boff);
    }

    for (int k0 = kb; k0 < kb + KSPAN; k0 += 64) {
        // commit prefetched step to LDS (swizzled granule)
        #pragma unroll
        for (int c = 0; c < 4; ++c) {
            int lo = (c * 32 + srow) * 64 + sgx;
            *(half8*)(lsA + lo) = pa[c];
            *(half8*)(lsB + lo) = pb[c];
            if constexpr (SPLIT) { *(half8*)(lsAl + lo) = pal[c]; *(half8*)(lsBl + lo) = pbl[c]; }
        }
        __syncthreads();
        // issue next step's global loads — overlap with the MFMA section below
        if (k0 + 64 < kb + KSPAN) {
            #pragma unroll
            for (int c = 0; c < 4; ++c) {
                int row = c * 32 + srow;
                bool mok = (row0 + row) < M;
                size_t aoff = (size_t)(row0 + row) * K + k0 + 64 + skk;
                pa[c] = mok ? *(const half8*)(Ah + aoff) : zer;
                if constexpr (SPLIT) pal[c] = mok ? *(const half8*)(Al + aoff) : zer;
                size_t boff = (size_t)(col0 + row) * K + k0 + 64 + skk;
                pb[c] = *(const half8*)(Bh + boff);
                if constexpr (SPLIT) pbl[c] = *(const half8*)(Bl + boff);
            }
        }
        #pragma unroll
        for (int kk = 0; kk < 2; ++kk) {
            half8 af[4], afl[4];
            #pragma unroll
            for (int mt = 0; mt < 4; ++mt) {
                int row = wm * 64 + mt * 16 + lr;
                int ao = row * 64 + (((kk * 4 + quad) ^ (row & 7)) << 3);
                af[mt] = *(const half8*)(lsA + ao);
                if constexpr (SPLIT) afl[mt] = *(const half8*)(lsAl + ao);
            }
            #pragma unroll
            for (int nt = 0; nt < 4; ++nt) {
                int row = wn * 64 + nt * 16 + lr;
                int bo = row * 64 + (((kk * 4 + quad) ^ (row & 7)) << 3);
                half8 bf = *(const half8*)(lsB + bo);
                half8 bfl;
                if constexpr (SPLIT) bfl = *(const half8*)(lsBl + bo);
                #pragma unroll
                for (int mt = 0; mt < 4; ++mt) {
                    acc[mt][nt] = __builtin_amdgcn_mfma_f32_16x16x32_f16(af[mt], bf, acc[mt][nt], 0, 0, 0);
                    if constexpr (SPLIT) {
                        acc[mt][nt] = __builtin_amdgcn_mfma_f32_16x16x32_f16(af[mt], bfl, acc[mt][nt], 0, 0, 0);
                        acc[mt][nt] = __builtin_amdgcn_mfma_f32_16x16x32_f16(afl[mt], bf, acc[mt][nt], 0, 0, 0);
                    }
                }
            }
        }
        __syncthreads();
    }

    size_t zoff = ACC ? (size_t)blockIdx.z * M * N : 0;
    #pragma unroll
    for (int mt = 0; mt < 4; ++mt) {
        #pragma unroll
        for (int rr = 0; rr < 4; ++rr) {
            int row = row0 + wm * 64 + mt * 16 + quad * 4 + rr;
            if (row >= M) continue;
            #pragma unroll
            for (int nt = 0; nt < 4; ++nt) {
                int col = col0 + wn * 64 + nt * 16 + lr;
                float v = acc[mt][nt][rr];
                if (!ACC) {
                    v += bias[col];
                    if (do_relu) v = v > 0.f ? v : 0.f;
                }
                if (outmode) Ch[((size_t)(col >> 5) * M + row) * 32 + (col & 31)] = f2h(v);
                else         C[zoff + (size_t)row * N + col] = v;
            }
        }
    }
}

// finish for split-K head: out = relu(sum_z partials + bias), vectorized float4
__global__ __launch_bounds__(256) void head_fin(const float* __restrict__ part, const float* __restrict__ bo,
                                                float* __restrict__ out) {
    int i4 = blockIdx.x * 256 + threadIdx.x;          // element-quad index
    const int TOT4 = NGRAPH * FPOUT / 4;
    if (i4 >= TOT4) return;
    int col4 = i4 & (FPOUT / 4 - 1);
    const size_t STRIDE4 = (size_t)NGRAPH * FPOUT / 4;
    const float4* p = (const float4*)part;
    float4 a = p[i4];
    float4 b = p[i4 + STRIDE4];
    float4 c = p[i4 + 2 * STRIDE4];
    float4 d = p[i4 + 3 * STRIDE4];
    float4 bb = ((const float4*)bo)[col4];
    float4 o;
    o.x = a.x + b.x + c.x + d.x + bb.x; o.x = o.x > 0.f ? o.x : 0.f;
    o.y = a.y + b.y + c.y + d.y + bb.y; o.y = o.y > 0.f ? o.y : 0.f;
    o.z = a.z + b.z + c.z + d.z + bb.z; o.z = o.z > 0.f ? o.z : 0.f;
    o.w = a.w + b.w + c.w + d.w + bb.w; o.w = o.w > 0.f ? o.w : 0.f;
    ((float4*)out)[i4] = o;
}

// ---------------- aggregation: feature-chunked, dense 16-nodes-per-wave, XCD-affine ----------------
// xh chunk-major [8][NNODES][32]. chunk = blockIdx.x & 7: round-robin blockIdx->XCD
// assignment pins chunk c to XCD c, so each XCD's random gathers hit its resident
// 3.2 MB slice (R5 measured: FETCH 58 MB vs 373 MB without affinity, R6).
// Wave: node = lane>>2 (16 nodes), quad = lane&3 (16B feature slot). Lane-local fp32
// accumulators (no reduce shuffles); trips = wave-max degree (4-step shfl_xor max).
// All 64 lanes gather (1KB/instr) and write. Bit-identical numerics to row-major agg.
__global__ __launch_bounds__(256) void agg_chunk(const ushort* __restrict__ xh, ushort* __restrict__ yh,
                                                 const float* __restrict__ dis,
                                                 const int* __restrict__ offs, const int2* __restrict__ csr_pair) {
    int wave = threadIdx.x >> 6;
    int lane = threadIdx.x & 63;
    int nd   = lane >> 2;               // node slot 0..15
    int quad = lane & 3;                // 16B quad within the 64B chunk row
    int chunk = blockIdx.x & 7;         // XCD-affine: chunk c -> XCD c (round-robin)
    int v = (blockIdx.x >> 3) * 64 + wave * 16 + nd;
    bool vok = v < NNODES;
    int vv = vok ? v : 0;
    int beg = offs[vv], end = offs[vv + 1];
    int deg = vok ? (end - beg) : 0;
    float dv = dis[vv];
    float sw = dv * dv;
    const _Float16* xc = (const _Float16*)xh + (size_t)chunk * NNODES * 32;

    // self-loop contribution
    half8 a0 = *(const half8*)(xc + (size_t)vv * 32 + quad * 8);
    float acc[8];
    #pragma unroll
    for (int j = 0; j < 8; ++j) acc[j] = (float)a0[j] * sw;

    // wave-max degree over the 16 node groups (quad bits untouched)
    int md = deg;
    #pragma unroll
    for (int m = 4; m <= 32; m <<= 1) {
        int o = __shfl_xor(md, m, 64);
        md = md > o ? md : o;
    }

    for (int t = 0; t < md; ++t) {
        bool val = t < deg;
        int ic = val ? beg + t : 0;
        int2 pr = csr_pair[ic];
        int s   = val ? pr.x : 0;
        float w = val ? __int_as_float(pr.y) : 0.f;
        half8 g = *(const half8*)(xc + (size_t)s * 32 + quad * 8);
        #pragma unroll
        for (int j = 0; j < 8; ++j) acc[j] += (float)g[j] * w;
    }

    if (vok) {
        ushort h[8];
        #pragma unroll
        for (int j = 0; j < 8; ++j) h[j] = f2h(acc[j]);
        short8 hv = {(short)h[0], (short)h[1], (short)h[2], (short)h[3],
                     (short)h[4], (short)h[5], (short)h[6], (short)h[7]};
        *(short8*)(yh + (size_t)v * 256 + chunk * 32 + quad * 8) = hv;
    }
}

// ---------------- fused gate+pool: per graph, 16 waves (BW-bound -> max occupancy) ----------------
__global__ __launch_bounds__(1024) void gatepool(const float* __restrict__ x, const float* __restrict__ pw,
                                                 const float* __restrict__ pb, const int* __restrict__ batch,
                                                 ushort* __restrict__ phi, ushort* __restrict__ plo, int n) {
    int g = blockIdx.x;
    int t = threadIdx.x;
    int wave = t >> 6, lane = t & 63;
    int lo_ = 0, hi_ = n;
    while (lo_ < hi_) { int mid = (lo_ + hi_) >> 1; if (batch[mid] < g) lo_ = mid + 1; else hi_ = mid; }
    int start = lo_;
    hi_ = n;
    while (lo_ < hi_) { int mid = (lo_ + hi_) >> 1; if (batch[mid] < g + 1) lo_ = mid + 1; else hi_ = mid; }
    int end = lo_;

    const float4* pwv = (const float4*)pw;
    float4 wa = pwv[lane], wb = pwv[lane + 64];
    float pb0 = pb[0];

    float4 s0 = make_float4(0.f, 0.f, 0.f, 0.f), s1 = s0;
    float4 m0 = make_float4(-INFINITY, -INFINITY, -INFINITY, -INFINITY), m1 = m0;

    for (int nn = start + wave; nn < end; nn += 16) {
        const float4* xr = (const float4*)(x + (size_t)nn * 512);
        float4 a = xr[lane];
        float4 b = xr[lane + 64];
        float p = a.x * wa.x + a.y * wa.y + a.z * wa.z + a.w * wa.w
                + b.x * wb.x + b.y * wb.y + b.z * wb.z + b.w * wb.w;
        #pragma unroll
        for (int off = 32; off; off >>= 1) p += __shfl_down(p, off, 64);
        float wg = __shfl(p, 0, 64);
        wg = 1.f / (1.f + expf(-(wg + pb0)));
        s0.x += a.x * wg; s0.y += a.y * wg; s0.z += a.z * wg; s0.w += a.w * wg;
        s1.x += b.x * wg; s1.y += b.y * wg; s1.z += b.z * wg; s1.w += b.w * wg;
        m0.x = fmaxf(m0.x, a.x); m0.y = fmaxf(m0.y, a.y); m0.z = fmaxf(m0.z, a.z); m0.w = fmaxf(m0.w, a.w);
        m1.x = fmaxf(m1.x, b.x); m1.y = fmaxf(m1.y, b.y); m1.z = fmaxf(m1.z, b.z); m1.w = fmaxf(m1.w, b.w);
    }

    __shared__ float ls[16][1024];
    *(float4*)&ls[wave][lane * 4]       = s0;
    *(float4*)&ls[wave][256 + lane * 4] = s1;
    *(float4*)&ls[wave][512 + lane * 4] = m0;
    *(float4*)&ls[wave][768 + lane * 4] = m1;
    __syncthreads();

    // thread t reduces one of the 1024 output slots across 16 waves
    float val;
    if (t < 512) {
        float s = 0.f;
        #pragma unroll
        for (int wv = 0; wv < 16; ++wv) s += ls[wv][t];
        val = s;
    } else {
        float m = -INFINITY;
        #pragma unroll
        for (int wv = 0; wv < 16; ++wv) m = fmaxf(m, ls[wv][t]);
        if (start >= end) m = 0.f;
        val = m;
    }
    ushort h, l;
    split2h(val, h, l);
    size_t base = (size_t)g * 1024;
    phi[base + t] = h;
    plo[base + t] = l;
}

// ---------------- launch ----------------

extern "C" void kernel_launch(void* const* d_in, const int* in_sizes, int n_in,
                              void* d_out, int out_size, void* d_ws, size_t ws_size,
                              hipStream_t stream) {
    const float* x0    = (const float*)d_in[0];
    const int*   ei    = (const int*)d_in[1];
    const int*   batch = (const int*)d_in[2];
    const float* W1 = (const float*)d_in[3];
    const float* b1 = (const float*)d_in[4];
    const float* W2 = (const float*)d_in[5];
    const float* b2 = (const float*)d_in[6];
    const float* W3 = (const float*)d_in[7];
    const float* b3 = (const float*)d_in[8];
    const float* pw = (const float*)d_in[9];
    const float* pb = (const float*)d_in[10];
    const float* Wo = (const float*)d_in[11];
    const float* bo = (const float*)d_in[12];
    float* out = (float*)d_out;

    // workspace layout (float units, 16B-aligned regions)
    float* ws = (float*)d_ws;
    size_t off = 0;
    float* bufB = ws + off; off += (size_t)NNODES * 512;                 // x3 fp32 / head split-K partials
    ushort* xh  = (ushort*)(ws + off); off += (size_t)NNODES * 256 / 2;  // activation fp16 table (chunk-major)
    ushort* yh  = (ushort*)(ws + off); off += (size_t)NNODES * 256 / 2;  // agg out fp16 (row-major)
    int*    rank = (int*)(ws + off);   off += (size_t)NNODES * 256 / 2;  // edge ranks
    ushort* W1thi = (ushort*)(ws + off); off += 256 * 256 / 2;
    ushort* W1tlo = (ushort*)(ws + off); off += 256 * 256 / 2;
    ushort* W2thi = (ushort*)(ws + off); off += 256 * 256 / 2;
    ushort* W2tlo = (ushort*)(ws + off); off += 256 * 256 / 2;
    ushort* W3thi = (ushort*)(ws + off); off += 512 * 256 / 2;
    ushort* W3tlo = (ushort*)(ws + off); off += 512 * 256 / 2;
    ushort* Wothi = (ushort*)(ws + off); off += (size_t)FPOUT * 1024 / 2;
    ushort* Wotlo = (ushort*)(ws + off); off += (size_t)FPOUT * 1024 / 2;
    ushort* phi = (ushort*)(ws + off); off += (size_t)NGRAPH * 1024 / 2;
    ushort* plo = (ushort*)(ws + off); off += (size_t)NGRAPH * 1024 / 2;
    float* dis  = ws + off; off += NNODES;
    int*   degi = (int*)(ws + off); off += NNODES;
    int*   offs = (int*)(ws + off); off += (NNODES + 4);
    int*   curs_unused = (int*)(ws + off); off += NNODES;
    (void)curs_unused;
    int2*  csr_pair = (int2*)(ws + off); off += 2 * (size_t)NEDGES;      // packed {src, w}
    int*   partials = (int*)(ws + off); off += 256;

    const int NB_N = (NNODES + 255) / 256;   // 196
    const int NB_E = (NEDGES + 255) / 256;
    const int MB128 = (NNODES + 127) / 128;  // 391
    const int NB_A = ((NNODES + 63) / 64) * 8;   // 782 node groups x 8 chunks, chunk = blk & 7

    // weight transpose+split (LDS-tiled, coalesced); layers use hi (= RNE fp16 W) only
    { dim3 g(256 / 32, 256 / 32);    wsplit_t<<<g, 256, 0, stream>>>(W1, W1thi, W1tlo, 256, 256); }
    { dim3 g(256 / 32, 256 / 32);    wsplit_t<<<g, 256, 0, stream>>>(W2, W2thi, W2tlo, 256, 256); }
    { dim3 g(512 / 32, 256 / 32);    wsplit_t<<<g, 256, 0, stream>>>(W3, W3thi, W3tlo, 256, 512); }
    { dim3 g(FPOUT / 32, 1024 / 32); wsplit_t<<<g, 256, 0, stream>>>(Wo, Wothi, Wotlo, 1024, FPOUT); }

    // CSR build (atomic-free scatter: rank captured in count_deg)
    zero_i32<<<NB_N, 256, 0, stream>>>(degi, NNODES);
    count_deg<<<NB_E, 256, 0, stream>>>(ei, degi, rank, NEDGES);
    calc_dis<<<NB_N, 256, 0, stream>>>(degi, dis, NNODES);
    scanA<<<NB_N, 256, 0, stream>>>(degi, offs, partials, NNODES);
    scanB<<<1, 256, 0, stream>>>(partials, NB_N);
    scanC<<<NB_N, 256, 0, stream>>>(offs, partials, NNODES);
    fill_csr<<<NB_E, 256, 0, stream>>>(ei, dis, offs, rank, csr_pair, NEDGES);

    // x0 -> fp16 table (chunk-major)
    conv_f16<<<(NNODES * 256 / 4 + 255) / 256, 256, 0, stream>>>(x0, xh, NNODES * 256 / 4);

    // layer 1: y = A_norm @ x0h ; x1h = fp16(relu(y @ W1 + b1)) (chunk-major)
    agg_chunk<<<NB_A, 256, 0, stream>>>(xh, yh, dis, offs, csr_pair);
    {
        dim3 grid(H1 / 128, MB128);
        gemm_f16<0, 0, 256><<<grid, 256, 0, stream>>>(yh, nullptr, W1thi, nullptr, nullptr, xh, b1,
                                                      NNODES, H1, FIN, 1, 1);
    }
    // layer 2
    agg_chunk<<<NB_A, 256, 0, stream>>>(xh, yh, dis, offs, csr_pair);
    {
        dim3 grid(H2 / 128, MB128);
        gemm_f16<0, 0, 256><<<grid, 256, 0, stream>>>(yh, nullptr, W2thi, nullptr, nullptr, xh, b2,
                                                      NNODES, H2, H1, 1, 1);
    }
    // layer 3: agg on x2h, GEMM 256->512 -> fp32 (gatepool input)
    agg_chunk<<<NB_A, 256, 0, stream>>>(xh, yh, dis, offs, csr_pair);
    {
        dim3 grid(H3 / 128, MB128);
        gemm_f16<0, 0, 256><<<grid, 256, 0, stream>>>(yh, nullptr, W3thi, nullptr, bufB, nullptr, b3,
                                                      NNODES, H3, H2, 1, 0);
    }
    // fused gate+pool -> pooled fp16 hi/lo (Dekker pairs)
    gatepool<<<NGRAPH, 1024, 0, stream>>>(bufB, pw, pb, batch, phi, plo, NNODES);
    // head: split-K over 4 z-slices into bufB partials (reused; gatepool is done with it),
    // then finish pass applies bias+relu.  3-term split-fp16 MFMA (~fp32 accurate).
    {
        dim3 grid(FPOUT / 128, (NGRAPH + 127) / 128, 4);
        gemm_f16<1, 1, 256><<<grid, 256, 0, stream>>>(phi, plo, Wothi, Wotlo, bufB, nullptr, nullptr,
                                                      NGRAPH, FPOUT, 1024, 0, 0);
    }
    head_fin<<<(NGRAPH * FPOUT / 4 + 255) / 256, 256, 0, stream>>>(bufB, bo, out);
}

// Round 8
// 539.092 us; speedup vs baseline: 1.4675x; 1.1697x over previous
//
#include <hip/hip_runtime.h>
#include <math.h>

#define NNODES 50000
#define NEDGES 800000
#define NGRAPH 512
#define FIN    256
#define H1     256
#define H2     256
#define H3     512
#define FPOUT  2048

#define NBUCK  196     // ceil(NNODES/256) coarse buckets (256 nodes each)
#define EPB    3200    // edges per binA block (250 blocks x 3200 = 800000 exactly)
#define BCAP   4864    // binB LDS chunk capacity (mean 4096, +12 sigma)

typedef __attribute__((ext_vector_type(8))) short short8;
typedef __attribute__((ext_vector_type(8))) _Float16 half8;
typedef __attribute__((ext_vector_type(4))) float floatx4;
typedef __attribute__((ext_vector_type(4))) unsigned short ushx4;

// fp16 helpers: v_cvt_f16_f32 is RNE on gfx950
__device__ inline float h2f(ushort u) { return (float)__builtin_bit_cast(_Float16, u); }
__device__ inline ushort f2h(float x) { return __builtin_bit_cast(ushort, (_Float16)x); }
// Dekker split: a = hi + lo with hi = RNE-fp16(a); lo carries ~11 more mantissa bits.
__device__ inline void split2h(float a, ushort& h, ushort& l) {
    _Float16 hh = (_Float16)a;
    h = __builtin_bit_cast(ushort, hh);
    l = f2h(a - (float)hh);
}

// ---------------- utility kernels ----------------

__global__ __launch_bounds__(256) void zero_i32(int* p, int n) {
    int i = blockIdx.x * 256 + threadIdx.x;
    if (i < n) p[i] = 0;
}

__global__ __launch_bounds__(256) void count_deg(const int* __restrict__ ei, int* __restrict__ degi, int e_total) {
    int e = blockIdx.x * 256 + threadIdx.x;
    if (e >= e_total) return;
    int d = ei[e_total + e];
    atomicAdd(&degi[d], 1);
}

__global__ __launch_bounds__(256) void calc_dis(const int* __restrict__ degi, float* __restrict__ dis, int n) {
    int i = blockIdx.x * 256 + threadIdx.x;
    if (i < n) dis[i] = rsqrtf((float)(degi[i] + 1));   // +1 self loop
}

__global__ __launch_bounds__(256) void scanA(const int* __restrict__ degi, int* __restrict__ offs,
                                             int* __restrict__ partials, int n) {
    __shared__ int sm[256];
    int t = threadIdx.x, idx = blockIdx.x * 256 + t;
    int v = (idx < n) ? degi[idx] : 0;
    sm[t] = v; __syncthreads();
    for (int d = 1; d < 256; d <<= 1) {
        int add = (t >= d) ? sm[t - d] : 0;
        __syncthreads();
        sm[t] += add;
        __syncthreads();
    }
    if (idx < n) offs[idx + 1] = sm[t];
    if (t == 255) partials[blockIdx.x] = sm[255];
}

__global__ __launch_bounds__(256) void scanB(int* __restrict__ partials, int nb) {
    __shared__ int sm[256];
    int t = threadIdx.x;
    int v = (t < nb) ? partials[t] : 0;
    sm[t] = v; __syncthreads();
    for (int d = 1; d < 256; d <<= 1) {
        int add = (t >= d) ? sm[t - d] : 0;
        __syncthreads();
        sm[t] += add;
        __syncthreads();
    }
    if (t < nb) partials[t] = sm[t] - v;   // exclusive
}

__global__ __launch_bounds__(256) void scanC(int* __restrict__ offs, const int* __restrict__ partials, int n) {
    int idx = blockIdx.x * 256 + threadIdx.x;
    if (idx < n) offs[idx + 1] += partials[blockIdx.x];
    if (idx == 0) offs[0] = 0;
}

// ---------------- CSR build via two-pass binning (kills scatter write amplification) ----
// binA: per block, LDS counting-sort 3200 edges by coarse bucket (d>>8, 256-node buckets),
// reserve global space with ONE atomic per (block,bucket), write runs contiguously.
// Old fill_csr: 800K random 8B scatters -> 83MB of partial-line HBM writes (R2 counters).
// Here every tmp write is part of a ~130B contiguous run -> ~1.2x amplification.
__global__ __launch_bounds__(256) void binA(const int* __restrict__ ei, const int* __restrict__ offs,
                                            int* __restrict__ gcur, int2* __restrict__ tmp, int e_total) {
    __shared__ int2 ls[EPB];
    __shared__ int2 ls2[EPB];
    __shared__ int hist[256], lpref[256], lcur[256], gbase[256], obase[256];
    int tid = threadIdx.x;
    int e0 = blockIdx.x * EPB;
    int cnt = e_total - e0; if (cnt > EPB) cnt = EPB;
    hist[tid] = 0;
    __syncthreads();
    for (int i = tid; i < cnt; i += 256) {
        int s = ei[e0 + i];
        int d = ei[e_total + e0 + i];
        ls[i] = (int2){s, d};
        atomicAdd(&hist[d >> 8], 1);
    }
    __syncthreads();
    // inclusive scan over 256 buckets -> exclusive
    int hv = hist[tid];
    lpref[tid] = hv;
    __syncthreads();
    for (int dlt = 1; dlt < 256; dlt <<= 1) {
        int add = (tid >= dlt) ? lpref[tid - dlt] : 0;
        __syncthreads();
        lpref[tid] += add;
        __syncthreads();
    }
    int excl = lpref[tid] - hv;
    __syncthreads();
    lpref[tid] = excl;
    lcur[tid] = 0;
    __syncthreads();
    // local reorder (stable enough; order within bucket is free)
    for (int i = tid; i < cnt; i += 256) {
        int2 pr = ls[i];
        int b = pr.y >> 8;
        int r = atomicAdd(&lcur[b], 1);
        ls2[lpref[b] + r] = pr;
    }
    // reserve global run space, fetch bucket bases
    if (tid < NBUCK) {
        int c = hist[tid];
        gbase[tid] = c ? atomicAdd(&gcur[tid], c) : 0;
        obase[tid] = offs[tid << 8];
    }
    __syncthreads();
    // coalesced run writes
    for (int i = tid; i < cnt; i += 256) {
        int2 pr = ls2[i];
        int b = pr.y >> 8;
        tmp[obase[b] + gbase[b] + (i - lpref[b])] = pr;
    }
}

// binB: per bucket, LDS-exact placement. Loads the bucket's edges chunk-wise into LDS,
// per-node LDS-atomic rank -> exact csr position offs[d]+r, computes weight, writes.
// All writes land in a ~32KB L2-held window -> full-line evictions (~6.4MB total).
__global__ __launch_bounds__(256) void binB(const int2* __restrict__ tmp, const int* __restrict__ offs,
                                            const float* __restrict__ dis, int2* __restrict__ csr_pair) {
    __shared__ int2 ls[BCAP];
    __shared__ int cntN[256];
    int tid = threadIdx.x;
    int b = blockIdx.x;
    int nlo = b << 8;
    int nhi = nlo + 256; if (nhi > NNODES) nhi = NNODES;
    int base = offs[nlo];
    int tot = offs[nhi] - base;
    cntN[tid] = 0;
    __syncthreads();
    for (int c0 = 0; c0 < tot; c0 += BCAP) {
        int cc = tot - c0; if (cc > BCAP) cc = BCAP;
        for (int i = tid; i < cc; i += 256)
            ls[i] = tmp[base + c0 + i];
        __syncthreads();
        for (int i = tid; i < cc; i += 256) {
            int2 pr = ls[i];
            int d = pr.y;
            int r = atomicAdd(&cntN[d & 255], 1);
            float w = dis[pr.x] * dis[d];
            csr_pair[offs[d] + r] = (int2){pr.x, __float_as_int(w)};
        }
        __syncthreads();
    }
}

// W[K][N] fp32 -> Wt_hi[N][K], Wt_lo[N][K] (fp16 Dekker pair): LDS-tiled transpose
__global__ __launch_bounds__(256) void wsplit_t(const float* __restrict__ W, ushort* __restrict__ hi,
                                                ushort* __restrict__ lo, int K, int N) {
    __shared__ float sm[32][33];
    int tx = threadIdx.x & 31, ty = threadIdx.x >> 5;   // 32 x 8
    int n0 = blockIdx.x * 32, k0 = blockIdx.y * 32;
    #pragma unroll
    for (int j = 0; j < 32; j += 8)
        sm[ty + j][tx] = W[(size_t)(k0 + ty + j) * N + n0 + tx];
    __syncthreads();
    #pragma unroll
    for (int j = 0; j < 32; j += 8) {
        float a = sm[tx][ty + j];
        ushort h, l; split2h(a, h, l);
        size_t o = (size_t)(n0 + ty + j) * K + k0 + tx;
        hi[o] = h; lo[o] = l;
    }
}

// x fp32 -> fp16-RNE table (row-major [NNODES][256])
__global__ __launch_bounds__(256) void conv_f16(const float* __restrict__ x, ushort* __restrict__ xh, int total4) {
    int i = blockIdx.x * 256 + threadIdx.x;
    if (i >= total4) return;
    float4 a = ((const float4*)x)[i];
    ushx4 h = {f2h(a.x), f2h(a.y), f2h(a.z), f2h(a.w)};
    ((ushx4*)xh)[i] = h;
}

// ---------------- MFMA fp16 GEMM: BK=64, XOR-swizzled LDS, XCD-chunked blocks ----------------
// SPLIT=0: C = relu(A @ B^T + bias), single fp16 operands, 1 MFMA per frag pair.
// SPLIT=1: fp16 Dekker pairs, 3 MFMAs: Ah*Bh + Ah*Bl + Al*Bh (~fp32-accurate). Head GEMM.
// ACC=1: store raw acc to partial buffer C + z*M*N (split-K, finish kernel applies bias/relu).
// outmode 1: write fp16 activation table row-major [M][N].
template<int SPLIT, int ACC, int KSPAN>
__global__ __launch_bounds__(256) void gemm_f16(const ushort* __restrict__ Ahp, const ushort* __restrict__ Alp,
                                                const ushort* __restrict__ Bhp, const ushort* __restrict__ Blp,
                                                float* __restrict__ C, ushort* __restrict__ Ch,
                                                const float* __restrict__ bias,
                                                int M, int N, int K, int do_relu, int outmode) {
    __shared__ _Float16 lsA[128 * 64];
    __shared__ _Float16 lsB[128 * 64];
    __shared__ _Float16 lsAl[SPLIT ? 128 * 64 : 8];
    __shared__ _Float16 lsBl[SPLIT ? 128 * 64 : 8];
    const _Float16* Ah = (const _Float16*)Ahp;
    const _Float16* Al = (const _Float16*)Alp;
    const _Float16* Bh = (const _Float16*)Bhp;
    const _Float16* Bl = (const _Float16*)Blp;

    int tid = threadIdx.x;
    int w = tid >> 6, lane = tid & 63;
    int quad = lane >> 4, lr = lane & 15;
    int wm = w & 1, wn = w >> 1;

    // bijective XCD-chunked swizzle (m204): same row-panel's col-tiles land on one XCD
    int gx = gridDim.x;
    int orig = blockIdx.y * gx + blockIdx.x;
    int nwg = gx * gridDim.y;
    int xcd = orig & 7, slot = orig >> 3;
    int q = nwg >> 3, r = nwg & 7;
    int wid = (xcd < r ? xcd * (q + 1) : r * (q + 1) + (xcd - r) * q) + slot;
    int row0 = (wid / gx) * 128, col0 = (wid % gx) * 128;
    int kb = blockIdx.z * KSPAN;

    floatx4 acc[4][4];
    #pragma unroll
    for (int i = 0; i < 4; ++i)
        #pragma unroll
        for (int j = 0; j < 4; ++j)
            acc[i][j] = (floatx4){0.f, 0.f, 0.f, 0.f};

    const half8 zer = {};
    int srow = tid >> 3;                         // 0..31 (chunk adds +32)
    int sgran = tid & 7;                         // logical 16B granule within BK=64
    int skk = sgran * 8;                         // logical k offset (halves)
    int sgx = (sgran ^ (srow & 7)) * 8;          // swizzled LDS granule offset (halves)

    half8 pa[4], pb[4], pal[4], pbl[4];
    // prologue: load k-step 0
    #pragma unroll
    for (int c = 0; c < 4; ++c) {
        int row = c * 32 + srow;
        bool mok = (row0 + row) < M;
        size_t aoff = (size_t)(row0 + row) * K + kb + skk;
        pa[c] = mok ? *(const half8*)(Ah + aoff) : zer;
        if constexpr (SPLIT) pal[c] = mok ? *(const half8*)(Al + aoff) : zer;
        size_t boff = (size_t)(col0 + row) * K + kb + skk;
        pb[c] = *(const half8*)(Bh + boff);
        if constexpr (SPLIT) pbl[c] = *(const half8*)(Bl + boff);
    }

    for (int k0 = kb; k0 < kb + KSPAN; k0 += 64) {
        // commit prefetched step to LDS (swizzled granule)
        #pragma unroll
        for (int c = 0; c < 4; ++c) {
            int lo = (c * 32 + srow) * 64 + sgx;
            *(half8*)(lsA + lo) = pa[c];
            *(half8*)(lsB + lo) = pb[c];
            if constexpr (SPLIT) { *(half8*)(lsAl + lo) = pal[c]; *(half8*)(lsBl + lo) = pbl[c]; }
        }
        __syncthreads();
        // issue next step's global loads — overlap with the MFMA section below
        if (k0 + 64 < kb + KSPAN) {
            #pragma unroll
            for (int c = 0; c < 4; ++c) {
                int row = c * 32 + srow;
                bool mok = (row0 + row) < M;
                size_t aoff = (size_t)(row0 + row) * K + k0 + 64 + skk;
                pa[c] = mok ? *(const half8*)(Ah + aoff) : zer;
                if constexpr (SPLIT) pal[c] = mok ? *(const half8*)(Al + aoff) : zer;
                size_t boff = (size_t)(col0 + row) * K + k0 + 64 + skk;
                pb[c] = *(const half8*)(Bh + boff);
                if constexpr (SPLIT) pbl[c] = *(const half8*)(Bl + boff);
            }
        }
        #pragma unroll
        for (int kk = 0; kk < 2; ++kk) {
            half8 af[4], afl[4];
            #pragma unroll
            for (int mt = 0; mt < 4; ++mt) {
                int row = wm * 64 + mt * 16 + lr;
                int ao = row * 64 + (((kk * 4 + quad) ^ (row & 7)) << 3);
                af[mt] = *(const half8*)(lsA + ao);
                if constexpr (SPLIT) afl[mt] = *(const half8*)(lsAl + ao);
            }
            #pragma unroll
            for (int nt = 0; nt < 4; ++nt) {
                int row = wn * 64 + nt * 16 + lr;
                int bo = row * 64 + (((kk * 4 + quad) ^ (row & 7)) << 3);
                half8 bf = *(const half8*)(lsB + bo);
                half8 bfl;
                if constexpr (SPLIT) bfl = *(const half8*)(lsBl + bo);
                #pragma unroll
                for (int mt = 0; mt < 4; ++mt) {
                    acc[mt][nt] = __builtin_amdgcn_mfma_f32_16x16x32_f16(af[mt], bf, acc[mt][nt], 0, 0, 0);
                    if constexpr (SPLIT) {
                        acc[mt][nt] = __builtin_amdgcn_mfma_f32_16x16x32_f16(af[mt], bfl, acc[mt][nt], 0, 0, 0);
                        acc[mt][nt] = __builtin_amdgcn_mfma_f32_16x16x32_f16(afl[mt], bf, acc[mt][nt], 0, 0, 0);
                    }
                }
            }
        }
        __syncthreads();
    }

    size_t zoff = ACC ? (size_t)blockIdx.z * M * N : 0;
    #pragma unroll
    for (int mt = 0; mt < 4; ++mt) {
        #pragma unroll
        for (int rr = 0; rr < 4; ++rr) {
            int row = row0 + wm * 64 + mt * 16 + quad * 4 + rr;
            if (row >= M) continue;
            #pragma unroll
            for (int nt = 0; nt < 4; ++nt) {
                int col = col0 + wn * 64 + nt * 16 + lr;
                float v = acc[mt][nt][rr];
                if (!ACC) {
                    v += bias[col];
                    if (do_relu) v = v > 0.f ? v : 0.f;
                }
                if (outmode) Ch[(size_t)row * N + col] = f2h(v);
                else         C[zoff + (size_t)row * N + col] = v;
            }
        }
    }
}

// finish for split-K head: out = relu(sum_z partials + bias), vectorized float4
__global__ __launch_bounds__(256) void head_fin(const float* __restrict__ part, const float* __restrict__ bo,
                                                float* __restrict__ out) {
    int i4 = blockIdx.x * 256 + threadIdx.x;          // element-quad index
    const int TOT4 = NGRAPH * FPOUT / 4;
    if (i4 >= TOT4) return;
    int col4 = i4 & (FPOUT / 4 - 1);
    const size_t STRIDE4 = (size_t)NGRAPH * FPOUT / 4;
    const float4* p = (const float4*)part;
    float4 a = p[i4];
    float4 b = p[i4 + STRIDE4];
    float4 c = p[i4 + 2 * STRIDE4];
    float4 d = p[i4 + 3 * STRIDE4];
    float4 bb = ((const float4*)bo)[col4];
    float4 o;
    o.x = a.x + b.x + c.x + d.x + bb.x; o.x = o.x > 0.f ? o.x : 0.f;
    o.y = a.y + b.y + c.y + d.y + bb.y; o.y = o.y > 0.f ? o.y : 0.f;
    o.z = a.z + b.z + c.z + d.z + bb.z; o.z = o.z > 0.f ? o.z : 0.f;
    o.w = a.w + b.w + c.w + d.w + bb.w; o.w = o.w > 0.f ? o.w : 0.f;
    ((float4*)out)[i4] = o;
}

// ---------------- aggregation: row-major fp16 gather, 2 nodes per wave (R4, 59.5us) -------
// y[v] = sum_{s->v} xh[s]*w + xh[v]*dis[v]^2, fp32 accumulate, fp16 output.
__global__ __launch_bounds__(256) void agg256b(const ushort* __restrict__ xh, ushort* __restrict__ yh,
                                               const float* __restrict__ dis,
                                               const int* __restrict__ offs, const int2* __restrict__ csr_pair) {
    constexpr int F = 256;
    int wave = threadIdx.x >> 6;
    int lane = threadIdx.x & 63;
    int half = lane >> 5;
    int sub  = lane & 31;                       // covers ushorts sub*8 .. sub*8+8
    int v = blockIdx.x * 8 + wave * 2 + half;   // 50000 % 8 == 0 -> always < NNODES
    int beg = offs[v], end = offs[v + 1];
    int len = end - beg;
    int leno = __shfl_xor(len, 32, 64);
    int maxlen = len > leno ? len : leno;       // uniform across wave

    float dv = dis[v];
    float sw = dv * dv;
    short8 a0 = ((const short8*)(xh + (size_t)v * F))[sub];
    float acc[8];
    #pragma unroll
    for (int j = 0; j < 8; ++j) acc[j] = h2f((ushort)a0[j]) * sw;

    for (int k = 0; k < maxlen; k += 8) {
        int   s[8];
        float w[8];
        #pragma unroll
        for (int u = 0; u < 8; ++u) {
            int idx = beg + k + u;
            bool val = idx < end;
            int ic = val ? idx : beg;
            int2 pr = csr_pair[ic];
            s[u] = pr.x;
            w[u] = val ? __int_as_float(pr.y) : 0.f;
        }
        short8 g[8];
        #pragma unroll
        for (int u = 0; u < 8; ++u)
            g[u] = ((const short8*)(xh + (size_t)s[u] * F))[sub];
        #pragma unroll
        for (int u = 0; u < 8; ++u) {
            #pragma unroll
            for (int j = 0; j < 8; ++j)
                acc[j] += h2f((ushort)g[u][j]) * w[u];
        }
    }

    ushort h[8];
    #pragma unroll
    for (int j = 0; j < 8; ++j) h[j] = f2h(acc[j]);
    short8 hv = {(short)h[0], (short)h[1], (short)h[2], (short)h[3], (short)h[4], (short)h[5], (short)h[6], (short)h[7]};
    ((short8*)(yh + (size_t)v * F))[sub] = hv;
}

// ---------------- fused gate+pool: per graph, 16 waves (BW-bound -> max occupancy) ----------------
__global__ __launch_bounds__(1024) void gatepool(const float* __restrict__ x, const float* __restrict__ pw,
                                                 const float* __restrict__ pb, const int* __restrict__ batch,
                                                 ushort* __restrict__ phi, ushort* __restrict__ plo, int n) {
    int g = blockIdx.x;
    int t = threadIdx.x;
    int wave = t >> 6, lane = t & 63;
    int lo_ = 0, hi_ = n;
    while (lo_ < hi_) { int mid = (lo_ + hi_) >> 1; if (batch[mid] < g) lo_ = mid + 1; else hi_ = mid; }
    int start = lo_;
    hi_ = n;
    while (lo_ < hi_) { int mid = (lo_ + hi_) >> 1; if (batch[mid] < g + 1) lo_ = mid + 1; else hi_ = mid; }
    int end = lo_;

    const float4* pwv = (const float4*)pw;
    float4 wa = pwv[lane], wb = pwv[lane + 64];
    float pb0 = pb[0];

    float4 s0 = make_float4(0.f, 0.f, 0.f, 0.f), s1 = s0;
    float4 m0 = make_float4(-INFINITY, -INFINITY, -INFINITY, -INFINITY), m1 = m0;

    for (int nn = start + wave; nn < end; nn += 16) {
        const float4* xr = (const float4*)(x + (size_t)nn * 512);
        float4 a = xr[lane];
        float4 b = xr[lane + 64];
        float p = a.x * wa.x + a.y * wa.y + a.z * wa.z + a.w * wa.w
                + b.x * wb.x + b.y * wb.y + b.z * wb.z + b.w * wb.w;
        #pragma unroll
        for (int off = 32; off; off >>= 1) p += __shfl_down(p, off, 64);
        float wg = __shfl(p, 0, 64);
        wg = 1.f / (1.f + expf(-(wg + pb0)));
        s0.x += a.x * wg; s0.y += a.y * wg; s0.z += a.z * wg; s0.w += a.w * wg;
        s1.x += b.x * wg; s1.y += b.y * wg; s1.z += b.z * wg; s1.w += b.w * wg;
        m0.x = fmaxf(m0.x, a.x); m0.y = fmaxf(m0.y, a.y); m0.z = fmaxf(m0.z, a.z); m0.w = fmaxf(m0.w, a.w);
        m1.x = fmaxf(m1.x, b.x); m1.y = fmaxf(m1.y, b.y); m1.z = fmaxf(m1.z, b.z); m1.w = fmaxf(m1.w, b.w);
    }

    __shared__ float ls[16][1024];
    *(float4*)&ls[wave][lane * 4]       = s0;
    *(float4*)&ls[wave][256 + lane * 4] = s1;
    *(float4*)&ls[wave][512 + lane * 4] = m0;
    *(float4*)&ls[wave][768 + lane * 4] = m1;
    __syncthreads();

    // thread t reduces one of the 1024 output slots across 16 waves
    float val;
    if (t < 512) {
        float s = 0.f;
        #pragma unroll
        for (int wv = 0; wv < 16; ++wv) s += ls[wv][t];
        val = s;
    } else {
        float m = -INFINITY;
        #pragma unroll
        for (int wv = 0; wv < 16; ++wv) m = fmaxf(m, ls[wv][t]);
        if (start >= end) m = 0.f;
        val = m;
    }
    ushort h, l;
    split2h(val, h, l);
    size_t base = (size_t)g * 1024;
    phi[base + t] = h;
    plo[base + t] = l;
}

// ---------------- launch ----------------

extern "C" void kernel_launch(void* const* d_in, const int* in_sizes, int n_in,
                              void* d_out, int out_size, void* d_ws, size_t ws_size,
                              hipStream_t stream) {
    const float* x0    = (const float*)d_in[0];
    const int*   ei    = (const int*)d_in[1];
    const int*   batch = (const int*)d_in[2];
    const float* W1 = (const float*)d_in[3];
    const float* b1 = (const float*)d_in[4];
    const float* W2 = (const float*)d_in[5];
    const float* b2 = (const float*)d_in[6];
    const float* W3 = (const float*)d_in[7];
    const float* b3 = (const float*)d_in[8];
    const float* pw = (const float*)d_in[9];
    const float* pb = (const float*)d_in[10];
    const float* Wo = (const float*)d_in[11];
    const float* bo = (const float*)d_in[12];
    float* out = (float*)d_out;

    // workspace layout (float units, 16B-aligned regions)
    float* ws = (float*)d_ws;
    size_t off = 0;
    float* bufB = ws + off; off += (size_t)NNODES * 512;                 // x3 fp32 / head split-K partials
    ushort* xh  = (ushort*)(ws + off); off += (size_t)NNODES * 256 / 2;  // activation fp16 table (row-major)
    ushort* yh  = (ushort*)(ws + off); off += (size_t)NNODES * 256 / 2;  // agg out fp16 (row-major)
    int2*   tmp = (int2*)(ws + off);   off += (size_t)NNODES * 256 / 2;  // binA {s,d} intermediate (6.4MB used)
    ushort* W1thi = (ushort*)(ws + off); off += 256 * 256 / 2;
    ushort* W1tlo = (ushort*)(ws + off); off += 256 * 256 / 2;
    ushort* W2thi = (ushort*)(ws + off); off += 256 * 256 / 2;
    ushort* W2tlo = (ushort*)(ws + off); off += 256 * 256 / 2;
    ushort* W3thi = (ushort*)(ws + off); off += 512 * 256 / 2;
    ushort* W3tlo = (ushort*)(ws + off); off += 512 * 256 / 2;
    ushort* Wothi = (ushort*)(ws + off); off += (size_t)FPOUT * 1024 / 2;
    ushort* Wotlo = (ushort*)(ws + off); off += (size_t)FPOUT * 1024 / 2;
    ushort* phi = (ushort*)(ws + off); off += (size_t)NGRAPH * 1024 / 2;
    ushort* plo = (ushort*)(ws + off); off += (size_t)NGRAPH * 1024 / 2;
    float* dis  = ws + off; off += NNODES;
    int*   degi = (int*)(ws + off); off += NNODES;
    int*   offs = (int*)(ws + off); off += (NNODES + 4);
    int*   gcur = (int*)(ws + off); off += 256;                          // binA bucket cursors
    int2*  csr_pair = (int2*)(ws + off); off += 2 * (size_t)NEDGES;      // packed {src, w}
    int*   partials = (int*)(ws + off); off += 256;

    const int NB_N = (NNODES + 255) / 256;   // 196
    const int NB_E = (NEDGES + 255) / 256;
    const int NB_A = NNODES / 8;             // 6250 blocks, wave = 2 nodes
    const int MB128 = (NNODES + 127) / 128;  // 391

    // weight transpose+split (LDS-tiled, coalesced); layers use hi (= RNE fp16 W) only
    { dim3 g(256 / 32, 256 / 32);    wsplit_t<<<g, 256, 0, stream>>>(W1, W1thi, W1tlo, 256, 256); }
    { dim3 g(256 / 32, 256 / 32);    wsplit_t<<<g, 256, 0, stream>>>(W2, W2thi, W2tlo, 256, 256); }
    { dim3 g(512 / 32, 256 / 32);    wsplit_t<<<g, 256, 0, stream>>>(W3, W3thi, W3tlo, 256, 512); }
    { dim3 g(FPOUT / 32, 1024 / 32); wsplit_t<<<g, 256, 0, stream>>>(Wo, Wothi, Wotlo, 1024, FPOUT); }

    // CSR build: degree count -> offsets -> two-pass binning (no fine-grained scatter)
    zero_i32<<<NB_N, 256, 0, stream>>>(degi, NNODES);
    count_deg<<<NB_E, 256, 0, stream>>>(ei, degi, NEDGES);
    calc_dis<<<NB_N, 256, 0, stream>>>(degi, dis, NNODES);
    scanA<<<NB_N, 256, 0, stream>>>(degi, offs, partials, NNODES);
    scanB<<<1, 256, 0, stream>>>(partials, NB_N);
    scanC<<<NB_N, 256, 0, stream>>>(offs, partials, NNODES);
    zero_i32<<<1, 256, 0, stream>>>(gcur, 256);
    binA<<<NEDGES / EPB, 256, 0, stream>>>(ei, offs, gcur, tmp, NEDGES);
    binB<<<NBUCK, 256, 0, stream>>>(tmp, offs, dis, csr_pair);

    // x0 -> fp16 table
    conv_f16<<<(NNODES * 256 / 4 + 255) / 256, 256, 0, stream>>>(x0, xh, NNODES * 256 / 4);

    // layer 1: y = A_norm @ x0h ; x1h = fp16(relu(y @ W1 + b1))
    agg256b<<<NB_A, 256, 0, stream>>>(xh, yh, dis, offs, csr_pair);
    {
        dim3 grid(H1 / 128, MB128);
        gemm_f16<0, 0, 256><<<grid, 256, 0, stream>>>(yh, nullptr, W1thi, nullptr, nullptr, xh, b1,
                                                      NNODES, H1, FIN, 1, 1);
    }
    // layer 2
    agg256b<<<NB_A, 256, 0, stream>>>(xh, yh, dis, offs, csr_pair);
    {
        dim3 grid(H2 / 128, MB128);
        gemm_f16<0, 0, 256><<<grid, 256, 0, stream>>>(yh, nullptr, W2thi, nullptr, nullptr, xh, b2,
                                                      NNODES, H2, H1, 1, 1);
    }
    // layer 3: agg on x2h, GEMM 256->512 -> fp32 (gatepool input)
    agg256b<<<NB_A, 256, 0, stream>>>(xh, yh, dis, offs, csr_pair);
    {
        dim3 grid(H3 / 128, MB128);
        gemm_f16<0, 0, 256><<<grid, 256, 0, stream>>>(yh, nullptr, W3thi, nullptr, bufB, nullptr, b3,
                                                      NNODES, H3, H2, 1, 0);
    }
    // fused gate+pool -> pooled fp16 hi/lo (Dekker pairs)
    gatepool<<<NGRAPH, 1024, 0, stream>>>(bufB, pw, pb, batch, phi, plo, NNODES);
    // head: split-K over 4 z-slices into bufB partials (reused; gatepool is done with it),
    // then finish pass applies bias+relu.  3-term split-fp16 MFMA (~fp32 accurate).
    {
        dim3 grid(FPOUT / 128, (NGRAPH + 127) / 128, 4);
        gemm_f16<1, 1, 256><<<grid, 256, 0, stream>>>(phi, plo, Wothi, Wotlo, bufB, nullptr, nullptr,
                                                      NGRAPH, FPOUT, 1024, 0, 0);
    }
    head_fin<<<(NGRAPH * FPOUT / 4 + 255) / 256, 256, 0, stream>>>(bufB, bo, out);
}